// Round 4
// baseline (666.237 us; speedup 1.0000x reference)
//
#include <hip/hip_runtime.h>
#include <hip/hip_cooperative_groups.h>
#include <math.h>

namespace cg = cooperative_groups;

// ---------------------------------------------------------------------------
// GraphTransformerLayer N=50000, E=640000, D=128, H=8, DH=16  (gfx950)
// Round 15: two cooperative mega-kernels (grid.sync between stages) replace
// the 10-dispatch chain; scatter+attn stay standalone (attn keeps its own
// occupancy). 4 dispatches total:
//   k_front (coop): zero -> prep casts | hist | qkv -> 2-phase scan
//   k_scatter, k_attn (unchanged R14)
//   k_back  (coop): oproj -> fold1 -> ffn1 -> ffn2 -> bn2
//
// Fragment order for an MxK slab (M=128, K=KB*32):
//   elem index = ((kb*8 + mtile)*64 + lane)*8 + j
//   row = mtile*16 + (lane&15),  col = kb*32 + (lane>>4)*8 + j
// Swapped-operand MFMA: mfma(Wfrag, hfrag) -> C^T: row = m*16+(lane&15),
// cols = w*32+nt*16+quad*4+{0..3} contiguous.
// ---------------------------------------------------------------------------

#define ND128 16384
typedef _Float16 f16;
typedef __attribute__((ext_vector_type(8))) _Float16 h8;
typedef __attribute__((ext_vector_type(4))) _Float16 h4;
typedef __attribute__((ext_vector_type(2))) _Float16 h2;
typedef __attribute__((ext_vector_type(4))) float f4;

__device__ __forceinline__ float fdot2h(h2 a, h2 b) {
#if __has_builtin(__builtin_amdgcn_fdot2)
    return __builtin_amdgcn_fdot2(a, b, 0.f, false);
#else
    return (float)a[0] * (float)b[0] + (float)a[1] * (float)b[1];
#endif
}

__device__ __forceinline__ float fast_exp2(float x) {
#if __has_builtin(__builtin_amdgcn_exp2f)
    return __builtin_amdgcn_exp2f(x);
#else
    return exp2f(x);
#endif
}

template <int CTRL>
__device__ __forceinline__ float dppadd(float x) {
    int t = __builtin_amdgcn_update_dpp(0, __float_as_int(x), CTRL, 0xF, 0xF, false);
    return x + __int_as_float(t);
}
__device__ __forceinline__ float wsum8(float p) {
    p = dppadd<0xB1>(p);
    p = dppadd<0x4E>(p);
    p = dppadd<0x141>(p);
    return p;
}

// ===========================================================================
// k_front (cooperative): S0 zero+prep casts / S1 hist+qkv / S2 two-phase scan
// ===========================================================================
__global__ __launch_bounds__(256) void k_front(
    const float* __restrict__ h, f16* __restrict__ hb,
    const float* __restrict__ WQ, const float* __restrict__ WK,
    const float* __restrict__ WV, const float* __restrict__ WO,
    const float* __restrict__ W2,
    f16* __restrict__ Wqb, f16* __restrict__ Wkb,
    f16* __restrict__ Wvb, f16* __restrict__ Wob, f16* __restrict__ W2b,
    f16* __restrict__ Qb, f16* __restrict__ KVb,
    int* __restrict__ cursor, int* __restrict__ rowptr,
    int* __restrict__ bsum, float* __restrict__ bn,
    const int* __restrict__ dst, int N, int E, int nhb, int nsb, int slabs)
{
    cg::grid_group grid = cg::this_grid();
    const int tid = threadIdx.x;
    const int G = gridDim.x;
    __shared__ int part[256];
    __shared__ int sboff_sh;

    // ---- S0: zero cursor/bn; cast h -> hb; cast weights ----
    for (int idx = blockIdx.x * 256 + tid; idx < N; idx += G * 256) cursor[idx] = 0;
    if (blockIdx.x == 0) { bn[tid] = 0.f; bn[tid + 256] = 0.f; }
    const int U0 = slabs * 2 + 6;
    for (int u = blockIdx.x; u < U0; u += G) {
        if (u < slabs * 2) {
            const int slab = u >> 1, my = u & 1;
#pragma unroll
            for (int it2 = 0; it2 < 4; ++it2) {
                int it = my * 4 + it2;
                int cid = it * 256 + tid;
                int lane = cid & 63;
                int m = (cid >> 6) & 7;
                int kb = cid >> 9;
                int row = slab * 128 + m * 16 + (lane & 15);
                int col = kb * 32 + (lane >> 4) * 8;
                f16 o8[8];
                if (row < N) {
                    const float* pp = h + (size_t)row * 128 + col;
                    float4 f0 = *(const float4*)pp;
                    float4 f1 = *(const float4*)(pp + 4);
                    o8[0] = (f16)f0.x; o8[1] = (f16)f0.y; o8[2] = (f16)f0.z; o8[3] = (f16)f0.w;
                    o8[4] = (f16)f1.x; o8[5] = (f16)f1.y; o8[6] = (f16)f1.z; o8[7] = (f16)f1.w;
                } else {
#pragma unroll
                    for (int j = 0; j < 8; ++j) o8[j] = (f16)0.f;
                }
                *(h8*)(hb + (size_t)slab * ND128 + (size_t)cid * 8) = *(const h8*)o8;
            }
        } else {
            const int ws = u - slabs * 2;          // 0..5
            const float* Wsrc; f16* dstw; int K, base;
            if (ws < 4) {
                Wsrc = ws == 0 ? WQ : ws == 1 ? WK : ws == 2 ? WV : WO;
                dstw = ws == 0 ? Wqb : ws == 1 ? Wkb : ws == 2 ? Wvb : Wob;
                K = 128; base = 0;
            } else {
                Wsrc = W2; dstw = W2b; K = 256; base = (ws - 4) * 2048;
            }
#pragma unroll
            for (int it = 0; it < 8; ++it) {
                int cid = base + it * 256 + tid;
                int lane = cid & 63;
                int kb, nt;
                if (K == 128) { kb = (cid >> 6) & 3; nt = cid >> 8; }
                else          { kb = (cid >> 6) & 7; nt = cid >> 9; }
                int row = nt * 16 + (lane & 15);
                int col = kb * 32 + (lane >> 4) * 8;
                const float* pp = Wsrc + (size_t)row * K + col;
                f16 o8[8];
#pragma unroll
                for (int j = 0; j < 8; ++j) o8[j] = (f16)pp[j];
                *(h8*)(dstw + (size_t)cid * 8) = *(const h8*)o8;
            }
        }
    }
    grid.sync();

    // ---- S1: hist (units [0,nhb)) + qkv (units [nhb, nhb+slabs*6)) ----
    const int U1 = nhb + slabs * 6;
    for (int u = blockIdx.x; u < U1; u += G) {
        if (u < nhb) {
            int e = u * 256 + tid;
            if (e < E) atomicAdd(&cursor[dst[e]], 1);
        } else {
            const int b2 = u - nhb;
            const int slab = b2 / 6, r6 = b2 % 6;
            const int oidx = r6 >> 1, mh = r6 & 1;
            const int w = tid >> 6, lane = tid & 63;
            const f16* __restrict__ Wb = oidx == 0 ? Wqb : oidx == 1 ? Wkb : Wvb;
            const f16* A = hb + (size_t)slab * ND128;

            h8 bfr[2][4];
#pragma unroll
            for (int nt = 0; nt < 2; ++nt)
#pragma unroll
                for (int kb = 0; kb < 4; ++kb)
                    bfr[nt][kb] = *(const h8*)(Wb + (size_t)(((2 * w + nt) * 4 + kb) * 64 + lane) * 8);

            f4 acc[4][2];
            f4 zero = {0.f, 0.f, 0.f, 0.f};
#pragma unroll
            for (int m = 0; m < 4; ++m) { acc[m][0] = zero; acc[m][1] = zero; }
#pragma unroll
            for (int m = 0; m < 4; ++m) {
                int mg = mh * 4 + m;
#pragma unroll
                for (int kb = 0; kb < 4; ++kb) {
                    h8 a = *(const h8*)(A + (size_t)((kb * 8 + mg) * 64 + lane) * 8);
                    acc[m][0] = __builtin_amdgcn_mfma_f32_16x16x32_f16(bfr[0][kb], a, acc[m][0], 0, 0, 0);
                    acc[m][1] = __builtin_amdgcn_mfma_f32_16x16x32_f16(bfr[1][kb], a, acc[m][1], 0, 0, 0);
                }
            }
            const int rl = lane & 15, quad = lane >> 4;
#pragma unroll
            for (int m = 0; m < 4; ++m) {
                int gr = slab * 128 + (mh * 4 + m) * 16 + rl;
                if (gr < N) {
#pragma unroll
                    for (int nt = 0; nt < 2; ++nt) {
                        h4 o;
                        o[0] = (f16)acc[m][nt][0]; o[1] = (f16)acc[m][nt][1];
                        o[2] = (f16)acc[m][nt][2]; o[3] = (f16)acc[m][nt][3];
                        int col = w * 32 + nt * 16 + quad * 4;
                        if (oidx == 0) {
                            *(h4*)(Qb + (size_t)gr * 128 + col) = o;
                        } else {
                            *(h4*)(KVb + (size_t)gr * 256 + (oidx == 1 ? col : 128 + col)) = o;
                        }
                    }
                }
            }
        }
    }
    grid.sync();

    // ---- S2a: per-scan-block partial sums ----
    if (blockIdx.x < (unsigned)nsb) {
        int base = blockIdx.x * 2048 + tid * 8;
        int s = 0;
#pragma unroll
        for (int j = 0; j < 8; ++j) {
            int idx = base + j;
            if (idx < N) s += cursor[idx];
        }
        part[tid] = s;
        __syncthreads();
        for (int off = 128; off; off >>= 1) {
            if (tid < off) part[tid] += part[tid + off];
            __syncthreads();
        }
        if (tid == 0) bsum[blockIdx.x] = part[0];
    }
    grid.sync();

    // ---- S2b: finalize scan; write rowptr + cursor ----
    if (blockIdx.x < (unsigned)nsb) {
        const int b = blockIdx.x;
        int base = b * 2048 + tid * 8;
        int loc[8];
        int s = 0;
#pragma unroll
        for (int j = 0; j < 8; ++j) {
            int idx = base + j;
            loc[j] = (idx < N) ? cursor[idx] : 0;
            s += loc[j];
        }
        part[tid] = s;
        __syncthreads();
        for (int off = 1; off < 256; off <<= 1) {
            int v = (tid >= off) ? part[tid - off] : 0;
            __syncthreads();
            part[tid] += v;
            __syncthreads();
        }
        if (tid == 0) {
            int prev = 0;
            for (int i2 = 0; i2 < b; ++i2) prev += bsum[i2];
            sboff_sh = prev;
            if (b == nsb - 1) rowptr[N] = prev + part[255];
        }
        __syncthreads();
        int run = sboff_sh + (tid ? part[tid - 1] : 0);
#pragma unroll
        for (int j = 0; j < 8; ++j) {
            int idx = base + j;
            if (idx < N) { rowptr[idx] = run; cursor[idx] = run; run += loc[j]; }
        }
    }
}

// --- scatter edges into CSR ------------------------------------------------
__global__ __launch_bounds__(256) void k_scatter(
    const int* __restrict__ src, const int* __restrict__ dst,
    int* __restrict__ cursor, int* __restrict__ csr_src, int E)
{
    int e = blockIdx.x * 256 + threadIdx.x;
    if (e < E) {
        int pos = atomicAdd(&cursor[dst[e]], 1);
        csr_src[pos] = src[e];
    }
}

// --- attention: one wave per node, lane owns channels (2l, 2l+1). ----------
__global__ __launch_bounds__(256) void k_attn(
    const f16* __restrict__ Qb, const f16* __restrict__ KVb,
    const int* __restrict__ rowptr, const int* __restrict__ csr_src,
    f16* __restrict__ attnf, int N)
{
    const int node = blockIdx.x * 4 + (threadIdx.x >> 6);
    const int lane = threadIdx.x & 63;
    if (node >= N) return;
    const int beg = rowptr[node], end = rowptr[node + 1];

    h2 qs;
    {
        h2 q2 = ((const h2*)(Qb + (size_t)node * 128))[lane];
        const float SCL = 0.25f * 1.44269504f;
        qs[0] = (f16)((float)q2[0] * SCL);
        qs[1] = (f16)((float)q2[1] * SCL);
    }
    const float CLP = 5.f * 1.44269504f;

    const h2* __restrict__ KV2 = (const h2*)KVb;

    h2 accA, accB;
    accA[0] = (f16)0.f; accA[1] = (f16)0.f;
    accB[0] = (f16)0.f; accB[1] = (f16)0.f;
    float z = 0.f;

    int i = beg;
    for (; i + 7 < end; i += 8) {
        int s[8];
#pragma unroll
        for (int u = 0; u < 8; ++u) s[u] = csr_src[i + u];
        h2 kk[8], vv[8];
#pragma unroll
        for (int u = 0; u < 8; ++u) {
            const h2* row = KV2 + (size_t)s[u] * 128;
            kk[u] = row[lane];
            vv[u] = row[64 + lane];
        }
        float sc[8];
#pragma unroll
        for (int u = 0; u < 8; ++u) {
            float p = wsum8(fdot2h(qs, kk[u]));
            sc[u] = fast_exp2(fminf(fmaxf(p, -CLP), CLP));
        }
#pragma unroll
        for (int u = 0; u < 8; ++u) z += sc[u];
#pragma unroll
        for (int u = 0; u < 8; ++u) {
            h2 c; c[0] = (f16)sc[u]; c[1] = (f16)sc[u];
            if (u & 1) accB += c * vv[u]; else accA += c * vv[u];
        }
    }
    if (i + 3 < end) {
        int s[4];
#pragma unroll
        for (int u = 0; u < 4; ++u) s[u] = csr_src[i + u];
        h2 kk[4], vv[4];
#pragma unroll
        for (int u = 0; u < 4; ++u) {
            const h2* row = KV2 + (size_t)s[u] * 128;
            kk[u] = row[lane];
            vv[u] = row[64 + lane];
        }
#pragma unroll
        for (int u = 0; u < 4; ++u) {
            float p = wsum8(fdot2h(qs, kk[u]));
            float scu = fast_exp2(fminf(fmaxf(p, -CLP), CLP));
            z += scu;
            h2 c; c[0] = (f16)scu; c[1] = (f16)scu;
            if (u & 1) accB += c * vv[u]; else accA += c * vv[u];
        }
        i += 4;
    }
    for (; i < end; ++i) {
        int s0 = csr_src[i];
        const h2* row = KV2 + (size_t)s0 * 128;
        h2 k0 = row[lane];
        h2 v0 = row[64 + lane];
        float p0 = wsum8(fdot2h(qs, k0));
        float sc0 = fast_exp2(fminf(fmaxf(p0, -CLP), CLP));
        z += sc0;
        h2 c0; c0[0] = (f16)sc0; c0[1] = (f16)sc0;
        accA += c0 * v0;
    }

    float inv = 1.f / z;
    float ax = ((float)accA[0] + (float)accB[0]) * inv;
    float ay = ((float)accA[1] + (float)accB[1]) * inv;
    h2 o2;
    o2[0] = (f16)ax; o2[1] = (f16)ay;
    int slab = node >> 7, m = (node >> 4) & 7, lr = node & 15;
    int kb = lane >> 4, quad2 = (lane & 15) >> 2, j = (lane & 3) * 2;
    *(h2*)(attnf + (size_t)slab * ND128 +
           (size_t)(((kb * 8 + m) * 64 + lr + 16 * quad2) * 8 + j)) = o2;
}

// ===========================================================================
// k_back (cooperative): S5 oproj / S6 fold1 / S7 ffn1 / S8 ffn2 / S9 bn2
// ===========================================================================
__global__ __launch_bounds__(256) void k_back(
    const f16* __restrict__ attnf, const f16* __restrict__ Wob,
    const float* __restrict__ h, const float* __restrict__ bO,
    f16* __restrict__ t1b, float* __restrict__ bn,
    const float* __restrict__ g1, const float* __restrict__ bb1,
    const float* __restrict__ W1, const float* __restrict__ b1,
    f16* __restrict__ W1b, float* __restrict__ badj,
    float* __restrict__ sfold, float* __restrict__ bfold,
    f16* __restrict__ ub, const f16* __restrict__ W2b,
    const float* __restrict__ b2, float* __restrict__ out,
    const float* __restrict__ g2, const float* __restrict__ bb2,
    int N, int slabs)
{
    cg::grid_group grid = cg::this_grid();
    const int tid = threadIdx.x;
    const int G = gridDim.x;
    const int w = tid >> 6, lane = tid & 63;
    const int rl = lane & 15, quad = lane >> 4;
    __shared__ float csum[128], csq[128], sS[128], sB[128];
    __shared__ float red[128];

    // ---- S5: oproj + BN1 sums ----
    {
        h8 bfr[2][4];
#pragma unroll
        for (int nt = 0; nt < 2; ++nt)
#pragma unroll
            for (int kb = 0; kb < 4; ++kb)
                bfr[nt][kb] = *(const h8*)(Wob + (size_t)(((2 * w + nt) * 4 + kb) * 64 + lane) * 8);
        float4 bo[2];
#pragma unroll
        for (int nt = 0; nt < 2; ++nt)
            bo[nt] = *(const float4*)(bO + w * 32 + nt * 16 + quad * 4);

        for (int u = blockIdx.x; u < slabs * 2; u += G) {
            const int slab = u >> 1, mh = u & 1;
            if (tid < 128) { csum[tid] = 0.f; csq[tid] = 0.f; }
            __syncthreads();
            const f16* A = attnf + (size_t)slab * ND128;

            f4 acc[4][2];
            f4 zero = {0.f, 0.f, 0.f, 0.f};
#pragma unroll
            for (int m = 0; m < 4; ++m) { acc[m][0] = zero; acc[m][1] = zero; }
#pragma unroll
            for (int m = 0; m < 4; ++m) {
                int mg = mh * 4 + m;
#pragma unroll
                for (int kb = 0; kb < 4; ++kb) {
                    h8 a = *(const h8*)(A + (size_t)((kb * 8 + mg) * 64 + lane) * 8);
                    acc[m][0] = __builtin_amdgcn_mfma_f32_16x16x32_f16(bfr[0][kb], a, acc[m][0], 0, 0, 0);
                    acc[m][1] = __builtin_amdgcn_mfma_f32_16x16x32_f16(bfr[1][kb], a, acc[m][1], 0, 0, 0);
                }
            }
            float pcs[2][4], pcq[2][4];
#pragma unroll
            for (int nt = 0; nt < 2; ++nt)
#pragma unroll
                for (int r = 0; r < 4; ++r) { pcs[nt][r] = 0.f; pcq[nt][r] = 0.f; }
#pragma unroll
            for (int m = 0; m < 4; ++m) {
                int mg = mh * 4 + m;
                int gr = slab * 128 + mg * 16 + rl;
                if (gr < N) {
#pragma unroll
                    for (int nt = 0; nt < 2; ++nt) {
                        int col0 = w * 32 + nt * 16 + quad * 4;
                        float4 hv = *(const float4*)(h + (size_t)gr * 128 + col0);
                        float v0 = acc[m][nt][0] + hv.x + bo[nt].x;
                        float v1 = acc[m][nt][1] + hv.y + bo[nt].y;
                        float v2 = acc[m][nt][2] + hv.z + bo[nt].z;
                        float v3 = acc[m][nt][3] + hv.w + bo[nt].w;
                        h4 o; o[0] = (f16)v0; o[1] = (f16)v1; o[2] = (f16)v2; o[3] = (f16)v3;
                        *(h4*)(t1b + (size_t)slab * ND128 +
                               (size_t)(((w * 8 + mg) * 64 + (nt * 2 + (quad >> 1)) * 16 + rl) * 8 +
                                        (quad & 1) * 4)) = o;
                        pcs[nt][0] += v0; pcq[nt][0] += v0 * v0;
                        pcs[nt][1] += v1; pcq[nt][1] += v1 * v1;
                        pcs[nt][2] += v2; pcq[nt][2] += v2 * v2;
                        pcs[nt][3] += v3; pcq[nt][3] += v3 * v3;
                    }
                }
            }
#pragma unroll
            for (int nt = 0; nt < 2; ++nt)
#pragma unroll
                for (int r = 0; r < 4; ++r) {
                    float s = pcs[nt][r], q = pcq[nt][r];
                    s += __shfl_xor(s, 8, 16); q += __shfl_xor(q, 8, 16);
                    s += __shfl_xor(s, 4, 16); q += __shfl_xor(q, 4, 16);
                    s += __shfl_xor(s, 2, 16); q += __shfl_xor(q, 2, 16);
                    s += __shfl_xor(s, 1, 16); q += __shfl_xor(q, 1, 16);
                    if (rl == 0) {
                        int cl = w * 32 + nt * 16 + quad * 4 + r;
                        atomicAdd(&csum[cl], s);
                        atomicAdd(&csq[cl], q);
                    }
                }
            __syncthreads();
            if (tid < 128) {
                atomicAdd(bn + tid, csum[tid]);
                atomicAdd(bn + 128 + tid, csq[tid]);
            }
            __syncthreads();
        }
    }
    grid.sync();

    // ---- S6: fold BN1 into W1/bias (256 row units) ----
    for (int u = blockIdx.x; u < 256; u += G) {
        const int o = u, i = tid & 127;
        if (tid < 128) {
            float invN = 1.f / (float)N;
            float mu = bn[i] * invN;
            float var = bn[128 + i] * invN - mu * mu;
            float s = g1[i] * rsqrtf(var + 1e-5f);
            float bb = bb1[i] - mu * s;
            if (o == 0) { sfold[i] = s; bfold[i] = bb; }
            float wv = W1[(size_t)o * 128 + i];
            red[i] = wv * bb;
            const int nt = o >> 4, lanelow = o & 15;
            const int kb = i >> 5, qq = (i >> 3) & 3, j = i & 7;
            W1b[(size_t)(((nt * 4 + kb) * 64 + lanelow + 16 * qq) * 8 + j)] = (f16)(wv * s);
        }
        __syncthreads();
        for (int off = 64; off; off >>= 1) {
            if (tid < off) red[tid] += red[tid + off];
            __syncthreads();
        }
        if (tid == 0) badj[o] = b1[o] + red[0];
        __syncthreads();
    }
    grid.sync();

    // ---- S7: FFN1 ----
    for (int u = blockIdx.x; u < slabs * 4; u += G) {
        const int slab = u >> 2, ch = (u >> 1) & 1, mh = u & 1;
        const f16* A = t1b + (size_t)slab * ND128;

        h8 bfr[2][4];
#pragma unroll
        for (int nt = 0; nt < 2; ++nt)
#pragma unroll
            for (int kb = 0; kb < 4; ++kb) {
                int ntg = ch * 8 + 2 * w + nt;
                bfr[nt][kb] = *(const h8*)(W1b + (size_t)((ntg * 4 + kb) * 64 + lane) * 8);
            }

        f4 acc[4][2];
        f4 zero = {0.f, 0.f, 0.f, 0.f};
#pragma unroll
        for (int m = 0; m < 4; ++m) { acc[m][0] = zero; acc[m][1] = zero; }
#pragma unroll
        for (int m = 0; m < 4; ++m) {
            int mg = mh * 4 + m;
#pragma unroll
            for (int kb = 0; kb < 4; ++kb) {
                h8 a = *(const h8*)(A + (size_t)((kb * 8 + mg) * 64 + lane) * 8);
                acc[m][0] = __builtin_amdgcn_mfma_f32_16x16x32_f16(bfr[0][kb], a, acc[m][0], 0, 0, 0);
                acc[m][1] = __builtin_amdgcn_mfma_f32_16x16x32_f16(bfr[1][kb], a, acc[m][1], 0, 0, 0);
            }
        }
        const int kbu = ch * 4 + w;
        float4 ba[2];
#pragma unroll
        for (int nt = 0; nt < 2; ++nt)
            ba[nt] = *(const float4*)(badj + ch * 128 + w * 32 + nt * 16 + quad * 4);
#pragma unroll
        for (int m = 0; m < 4; ++m) {
            int mg = mh * 4 + m;
            int gr = slab * 128 + mg * 16 + rl;
            if (gr < N) {
#pragma unroll
                for (int nt = 0; nt < 2; ++nt) {
                    h4 o;
                    o[0] = (f16)fmaxf(acc[m][nt][0] + ba[nt].x, 0.f);
                    o[1] = (f16)fmaxf(acc[m][nt][1] + ba[nt].y, 0.f);
                    o[2] = (f16)fmaxf(acc[m][nt][2] + ba[nt].z, 0.f);
                    o[3] = (f16)fmaxf(acc[m][nt][3] + ba[nt].w, 0.f);
                    *(h4*)(ub + (size_t)slab * 32768 +
                           (size_t)(((kbu * 8 + mg) * 64 + (nt * 2 + (quad >> 1)) * 16 + rl) * 8 +
                                    (quad & 1) * 4)) = o;
                }
            }
        }
    }
    grid.sync();

    // ---- S8: FFN2 + BN2 sums ----
    {
        h8 bfr[2][8];
#pragma unroll
        for (int nt = 0; nt < 2; ++nt)
#pragma unroll
            for (int kb = 0; kb < 8; ++kb)
                bfr[nt][kb] = *(const h8*)(W2b + (size_t)(((2 * w + nt) * 8 + kb) * 64 + lane) * 8);
        if (tid < 128) { sS[tid] = sfold[tid]; sB[tid] = bfold[tid] + b2[tid]; }
        __syncthreads();

        for (int u = blockIdx.x; u < slabs * 2; u += G) {
            const int slab = u >> 1, mh = u & 1;
            if (tid < 128) { csum[tid] = 0.f; csq[tid] = 0.f; }
            __syncthreads();
            const f16* A = ub + (size_t)slab * 32768;
            const f16* T1 = t1b + (size_t)slab * ND128;

            f4 acc[4][2];
            f4 zero = {0.f, 0.f, 0.f, 0.f};
#pragma unroll
            for (int m = 0; m < 4; ++m) { acc[m][0] = zero; acc[m][1] = zero; }
#pragma unroll
            for (int m = 0; m < 4; ++m) {
                int mg = mh * 4 + m;
#pragma unroll
                for (int kb = 0; kb < 8; ++kb) {
                    h8 a = *(const h8*)(A + (size_t)((kb * 8 + mg) * 64 + lane) * 8);
                    acc[m][0] = __builtin_amdgcn_mfma_f32_16x16x32_f16(bfr[0][kb], a, acc[m][0], 0, 0, 0);
                    acc[m][1] = __builtin_amdgcn_mfma_f32_16x16x32_f16(bfr[1][kb], a, acc[m][1], 0, 0, 0);
                }
            }
            float pcs[2][4], pcq[2][4];
#pragma unroll
            for (int nt = 0; nt < 2; ++nt)
#pragma unroll
                for (int r = 0; r < 4; ++r) { pcs[nt][r] = 0.f; pcq[nt][r] = 0.f; }
#pragma unroll
            for (int m = 0; m < 4; ++m) {
                int mg = mh * 4 + m;
                int gr = slab * 128 + mg * 16 + rl;
                if (gr < N) {
#pragma unroll
                    for (int nt = 0; nt < 2; ++nt) {
                        int col0 = w * 32 + nt * 16 + quad * 4;
                        h4 t1v = *(const h4*)(T1 +
                            (size_t)(((w * 8 + mg) * 64 + (nt * 2 + (quad >> 1)) * 16 + rl) * 8 +
                                     (quad & 1) * 4));
                        float4 ss = *(const float4*)&sS[col0];
                        float4 sb = *(const float4*)&sB[col0];
                        float4 o;
                        o.x = acc[m][nt][0] + fmaf(ss.x, (float)t1v[0], sb.x);
                        o.y = acc[m][nt][1] + fmaf(ss.y, (float)t1v[1], sb.y);
                        o.z = acc[m][nt][2] + fmaf(ss.z, (float)t1v[2], sb.z);
                        o.w = acc[m][nt][3] + fmaf(ss.w, (float)t1v[3], sb.w);
                        *(float4*)(out + (size_t)gr * 128 + col0) = o;
                        pcs[nt][0] += o.x; pcq[nt][0] += o.x * o.x;
                        pcs[nt][1] += o.y; pcq[nt][1] += o.y * o.y;
                        pcs[nt][2] += o.z; pcq[nt][2] += o.z * o.z;
                        pcs[nt][3] += o.w; pcq[nt][3] += o.w * o.w;
                    }
                }
            }
#pragma unroll
            for (int nt = 0; nt < 2; ++nt)
#pragma unroll
                for (int r = 0; r < 4; ++r) {
                    float s = pcs[nt][r], q = pcq[nt][r];
                    s += __shfl_xor(s, 8, 16); q += __shfl_xor(q, 8, 16);
                    s += __shfl_xor(s, 4, 16); q += __shfl_xor(q, 4, 16);
                    s += __shfl_xor(s, 2, 16); q += __shfl_xor(q, 2, 16);
                    s += __shfl_xor(s, 1, 16); q += __shfl_xor(q, 1, 16);
                    if (rl == 0) {
                        int cl = w * 32 + nt * 16 + quad * 4 + r;
                        atomicAdd(&csum[cl], s);
                        atomicAdd(&csq[cl], q);
                    }
                }
            __syncthreads();
            if (tid < 128) {
                atomicAdd(bn + 256 + tid, csum[tid]);
                atomicAdd(bn + 384 + tid, csq[tid]);
            }
            __syncthreads();
        }
    }
    grid.sync();

    // ---- S9: BN2 normalize in place ----
    if (tid < 128) {
        float invN = 1.f / (float)N;
        float mu = bn[256 + tid] * invN;
        float var = bn[384 + tid] * invN - mu * mu;
        float scl = g2[tid] * rsqrtf(var + 1e-5f);
        sS[tid] = scl;
        sB[tid] = bb2[tid] - mu * scl;
    }
    __syncthreads();
    const size_t total = (size_t)N * 32;
    const int U9 = (int)((total + 255) / 256);
    for (int u = blockIdx.x; u < U9; u += G) {
        size_t idx = (size_t)u * 256 + tid;
        if (idx < total) {
            int c0 = (int)((idx * 4) & 127);
            float4 v = *(const float4*)(out + idx * 4);
            v.x = fmaf(v.x, sS[c0 + 0], sB[c0 + 0]);
            v.y = fmaf(v.y, sS[c0 + 1], sB[c0 + 1]);
            v.z = fmaf(v.z, sS[c0 + 2], sB[c0 + 2]);
            v.w = fmaf(v.w, sS[c0 + 3], sB[c0 + 3]);
            *(float4*)(out + idx * 4) = v;
        }
    }
}

extern "C" void kernel_launch(void* const* d_in, const int* in_sizes, int n_in,
                              void* d_out, int out_size, void* d_ws, size_t ws_size,
                              hipStream_t stream)
{
    const float* h   = (const float*)d_in[0];
    const int*   src = (const int*)d_in[1];
    const int*   dst = (const int*)d_in[2];
    const float* WQ  = (const float*)d_in[3];
    const float* WK  = (const float*)d_in[4];
    const float* WV  = (const float*)d_in[5];
    const float* WO  = (const float*)d_in[6];
    const float* bO  = (const float*)d_in[7];
    const float* W1  = (const float*)d_in[8];
    const float* b1  = (const float*)d_in[9];
    const float* W2  = (const float*)d_in[10];
    const float* b2  = (const float*)d_in[11];
    const float* g1  = (const float*)d_in[12];
    const float* bb1 = (const float*)d_in[13];
    const float* g2  = (const float*)d_in[14];
    const float* bb2 = (const float*)d_in[15];
    float* out = (float*)d_out;

    int N = in_sizes[0] / 128;
    int E = in_sizes[1];
    int slabs = (N + 127) / 128;
    int nsb = (N + 2047) / 2048;               // scan blocks (~25)
    int nhb = (E + 255) / 256;                 // edge blocks (~2500)
    const size_t B1 = (size_t)slabs * 32768;   // bytes of one f16 N_pad x 128 buffer

    char* Wp = (char*)d_ws;
    f16* hb  = (f16*)Wp;                       // becomes attnf after attn
    f16* Qb  = (f16*)(Wp + B1);                // B1
    f16* KVb = (f16*)(Wp + 2 * B1);            // 2*B1 (f16 K|V interleaved rows)
    f16* ub  = (f16*)(Wp + B1);                // 2*B1, overlays Qb + KVb.K after attn
    f16* t1b = (f16*)(Wp + 3 * B1);            // B1, overlays KVb.V tail (dead after attn)
    const size_t base = 4 * B1;
    f16* Wqb = (f16*)(Wp + base);
    f16* Wkb = (f16*)(Wp + base + 32768);
    f16* Wvb = (f16*)(Wp + base + 65536);
    f16* Wob = (f16*)(Wp + base + 98304);
    f16* W1b = (f16*)(Wp + base + 131072);
    f16* W2b = (f16*)(Wp + base + 196608);
    float* badj  = (float*)(Wp + base + 262144);
    float* sfold = (float*)(Wp + base + 263168);
    float* bfold = (float*)(Wp + base + 263680);
    float* bn    = (float*)(Wp + base + 264192);     // 512 floats (zeroed in S0)
    int* bsum    = (int*)(Wp + base + 266240);       // 64 ints
    int* cursor  = (int*)(Wp + base + 266496);       // N ints (zeroed in S0)
    int* rowptr  = (int*)(Wp + base + 266496 + (size_t)N * 4);
    int* csr     = (int*)(Wp + base + 266496 + (size_t)N * 8 + 8);

    static int ncu = 0, nb1 = 0, nb2 = 0;
    if (ncu == 0) {
        int dev = 0;
        hipGetDevice(&dev);
        hipDeviceGetAttribute(&ncu, hipDeviceAttributeMultiprocessorCount, dev);
        hipOccupancyMaxActiveBlocksPerMultiprocessor(&nb1, k_front, 256, 0);
        hipOccupancyMaxActiveBlocksPerMultiprocessor(&nb2, k_back, 256, 0);
        if (ncu <= 0) ncu = 256;
        if (nb1 <= 0) nb1 = 1;
        if (nb2 <= 0) nb2 = 1;
    }
    int G1 = ncu * nb1; if (G1 > 2048) G1 = 2048;
    int G2 = ncu * nb2; if (G2 > 1024) G2 = 1024;
    if (G1 < nsb) G1 = nsb;

    {
        void* a1[] = {(void*)&h, (void*)&hb, (void*)&WQ, (void*)&WK, (void*)&WV,
                      (void*)&WO, (void*)&W2, (void*)&Wqb, (void*)&Wkb, (void*)&Wvb,
                      (void*)&Wob, (void*)&W2b, (void*)&Qb, (void*)&KVb,
                      (void*)&cursor, (void*)&rowptr, (void*)&bsum, (void*)&bn,
                      (void*)&dst, (void*)&N, (void*)&E, (void*)&nhb, (void*)&nsb,
                      (void*)&slabs};
        hipLaunchCooperativeKernel((void*)k_front, dim3(G1), dim3(256), a1, 0, stream);
    }
    k_scatter<<<nhb, 256, 0, stream>>>(src, dst, cursor, csr, E);
    k_attn<<<(N + 3) / 4, 256, 0, stream>>>(Qb, KVb, rowptr, csr, hb, N);
    {
        void* a2[] = {(void*)&hb, (void*)&Wob, (void*)&h, (void*)&bO, (void*)&t1b,
                      (void*)&bn, (void*)&g1, (void*)&bb1, (void*)&W1, (void*)&b1,
                      (void*)&W1b, (void*)&badj, (void*)&sfold, (void*)&bfold,
                      (void*)&ub, (void*)&W2b, (void*)&b2, (void*)&out,
                      (void*)&g2, (void*)&bb2, (void*)&N, (void*)&slabs};
        hipLaunchCooperativeKernel((void*)k_back, dim3(G2), dim3(256), a2, 0, stream);
    }
}

// Round 5
// 561.073 us; speedup vs baseline: 1.1874x; 1.1874x over previous
//
#include <hip/hip_runtime.h>
#include <math.h>

// ---------------------------------------------------------------------------
// GraphTransformerLayer N=50000, E=640000, D=128, H=8, DH=16  (gfx950)
// Round 16:
//  (a) attn = fp8 K/V storage (R11, half fetch) + cheap math (R13: DPP wsum8,
//      exp2 folded scale, HW cvt_pk_f32_fp8 decode, f32 accum).
//  (b) back half (oproj/fold1/ffn1/ffn2/bn2) fused into ONE cooperative
//      kernel using a HAND-ROLLED global barrier (atomic counter + s_sleep).
//      cg::grid_group::sync measured ~130us/sync in R15 -- never call it.
//  Front stays plain dispatches: memset, prep|hist, qkv, scanA, scanC,
//  scatter, attn.
//
// Fragment order for an MxK slab (M=128, K=KB*32):
//   elem index = ((kb*8 + mtile)*64 + lane)*8 + j
//   row = mtile*16 + (lane&15),  col = kb*32 + (lane>>4)*8 + j
// Swapped-operand MFMA: mfma(Wfrag, hfrag) -> C^T: row = m*16+(lane&15),
// cols = w*32+nt*16+quad*4+{0..3} contiguous.
// ---------------------------------------------------------------------------

#define ND128 16384
typedef _Float16 f16;
typedef __attribute__((ext_vector_type(8))) _Float16 h8;
typedef __attribute__((ext_vector_type(4))) _Float16 h4;
typedef __attribute__((ext_vector_type(2))) _Float16 h2;
typedef __attribute__((ext_vector_type(4))) float f4;
typedef __attribute__((ext_vector_type(2))) float ff2;

__device__ __forceinline__ float fast_exp2(float x) {
#if __has_builtin(__builtin_amdgcn_exp2f)
    return __builtin_amdgcn_exp2f(x);
#else
    return exp2f(x);
#endif
}

template <int CTRL>
__device__ __forceinline__ float dppadd(float x) {
    int t = __builtin_amdgcn_update_dpp(0, __float_as_int(x), CTRL, 0xF, 0xF, false);
    return x + __int_as_float(t);
}
__device__ __forceinline__ float wsum8(float p) {
    p = dppadd<0xB1>(p);    // quad_perm [1,0,3,2]
    p = dppadd<0x4E>(p);    // quad_perm [2,3,0,1]
    p = dppadd<0x141>(p);   // row_half_mirror
    return p;
}

__device__ __forceinline__ ff2 fp8x2_dec(unsigned v) {
#if __has_builtin(__builtin_amdgcn_cvt_pk_f32_fp8)
    return __builtin_amdgcn_cvt_pk_f32_fp8((int)v, false);
#else
    ff2 r;
    unsigned b0 = v & 0xffu, b1 = (v >> 8) & 0xffu;
    {
        unsigned e = (b0 >> 3) & 15u, m = b0 & 7u;
        float x = e ? __uint_as_float(((e + 120u) << 23) | (m << 20)) : (float)m * 0.001953125f;
        r.x = (b0 & 0x80u) ? -x : x;
    }
    {
        unsigned e = (b1 >> 3) & 15u, m = b1 & 7u;
        float x = e ? __uint_as_float(((e + 120u) << 23) | (m << 20)) : (float)m * 0.001953125f;
        r.y = (b1 & 0x80u) ? -x : x;
    }
    return r;
#endif
}

#if !__has_builtin(__builtin_amdgcn_cvt_pk_fp8_f32)
__device__ __forceinline__ unsigned char fp8_1(float f) {
    float a = fabsf(f);
    unsigned sg = (__float_as_uint(f) >> 31) << 7;
    if (a >= 448.f) return (unsigned char)(sg | 0x7E);
    if (a < 0.0009765625f) return (unsigned char)sg;
    int E; float m = frexpf(a, &E);
    if (E - 1 < -6) {
        int q = (int)rintf(a * 512.f);
        if (q > 7) return (unsigned char)(sg | 0x08);
        return (unsigned char)(sg | q);
    }
    int q = (int)rintf(m * 16.f);
    if (q == 16) { q = 8; E += 1; }
    int Ef = E - 1 + 7;
    if (Ef > 15) return (unsigned char)(sg | 0x7E);
    return (unsigned char)(sg | (Ef << 3) | (q - 8));
}
#endif

__device__ __forceinline__ unsigned fp8_pack4(float a0, float a1, float a2, float a3) {
#if __has_builtin(__builtin_amdgcn_cvt_pk_fp8_f32)
    int pk = __builtin_amdgcn_cvt_pk_fp8_f32(a0, a1, 0, false);
    pk = __builtin_amdgcn_cvt_pk_fp8_f32(a2, a3, pk, true);
    return (unsigned)pk;
#else
    return (unsigned)fp8_1(a0) | ((unsigned)fp8_1(a1) << 8) |
           ((unsigned)fp8_1(a2) << 16) | ((unsigned)fp8_1(a3) << 24);
#endif
}

// hand-rolled grid barrier: monotonic counter, agent scope, s_sleep backoff.
__device__ __forceinline__ void gbar(int* cnt, int ph) {
    __threadfence();
    __syncthreads();
    if (threadIdx.x == 0) {
        __hip_atomic_fetch_add(cnt, 1, __ATOMIC_ACQ_REL, __HIP_MEMORY_SCOPE_AGENT);
        const int target = (int)gridDim.x * ph;
        while (__hip_atomic_load(cnt, __ATOMIC_ACQUIRE, __HIP_MEMORY_SCOPE_AGENT) < target)
            __builtin_amdgcn_s_sleep(8);
    }
    __syncthreads();
}

// --- K1: hist (blocks [0,nhb)) UNION prep (blocks [nhb, nhb+slabs*2)). ----
__global__ __launch_bounds__(256) void k_prep_hist(
    const float* __restrict__ h, f16* __restrict__ hb,
    const float* __restrict__ WQ, const float* __restrict__ WK,
    const float* __restrict__ WV, const float* __restrict__ WO,
    const float* __restrict__ W2,
    f16* __restrict__ Wqb, f16* __restrict__ Wkb,
    f16* __restrict__ Wvb, f16* __restrict__ Wob, f16* __restrict__ W2b,
    int* __restrict__ cursor, const int* __restrict__ dst,
    int N, int E, int nhb)
{
    const int tid = threadIdx.x;
    if (blockIdx.x < (unsigned)nhb) {
        int e = blockIdx.x * 256 + tid;
        if (e < E) atomicAdd(&cursor[dst[e]], 1);
        return;
    }
    const int p = blockIdx.x - nhb;
    const int slab = p >> 1, my = p & 1;
#pragma unroll
    for (int it2 = 0; it2 < 4; ++it2) {
        int it = my * 4 + it2;
        int cid = it * 256 + tid;              // 0..2047
        int lane = cid & 63;
        int m = (cid >> 6) & 7;
        int kb = cid >> 9;
        int row = slab * 128 + m * 16 + (lane & 15);
        int col = kb * 32 + (lane >> 4) * 8;
        f16 o8[8];
        if (row < N) {
            const float* pp = h + (size_t)row * 128 + col;
            float4 f0 = *(const float4*)pp;
            float4 f1 = *(const float4*)(pp + 4);
            o8[0] = (f16)f0.x; o8[1] = (f16)f0.y; o8[2] = (f16)f0.z; o8[3] = (f16)f0.w;
            o8[4] = (f16)f1.x; o8[5] = (f16)f1.y; o8[6] = (f16)f1.z; o8[7] = (f16)f1.w;
        } else {
#pragma unroll
            for (int j = 0; j < 8; ++j) o8[j] = (f16)0.f;
        }
        *(h8*)(hb + (size_t)slab * ND128 + (size_t)cid * 8) = *(const h8*)o8;
    }
    if (slab < 6 && my == 1) {
        const float* Wsrc; f16* dstw; int K, base;
        if (slab < 4) {
            Wsrc = slab == 0 ? WQ : slab == 1 ? WK : slab == 2 ? WV : WO;
            dstw = slab == 0 ? Wqb : slab == 1 ? Wkb : slab == 2 ? Wvb : Wob;
            K = 128; base = 0;
        } else {
            Wsrc = W2; dstw = W2b; K = 256; base = (slab - 4) * 2048;
        }
#pragma unroll
        for (int it = 0; it < 8; ++it) {
            int cid = base + it * 256 + tid;
            int lane = cid & 63;
            int kb, nt;
            if (K == 128) { kb = (cid >> 6) & 3; nt = cid >> 8; }
            else          { kb = (cid >> 6) & 7; nt = cid >> 9; }
            int row = nt * 16 + (lane & 15);
            int col = kb * 32 + (lane >> 4) * 8;
            const float* pp = Wsrc + (size_t)row * K + col;
            f16 o8[8];
#pragma unroll
            for (int j = 0; j < 8; ++j) o8[j] = (f16)pp[j];
            *(h8*)(dstw + (size_t)cid * 8) = *(const h8*)o8;
        }
    }
}

// --- K2: QKV grid (slabs, 3, 2). Q f16 rows; K/V fp8 in 256B rows of KV8. -
__global__ __launch_bounds__(256) void k_qkv(
    const f16* __restrict__ hb, const f16* __restrict__ Wqb,
    const f16* __restrict__ Wkb, const f16* __restrict__ Wvb,
    f16* __restrict__ Qb, unsigned char* __restrict__ KV8, int N)
{
    const int slab = blockIdx.x, oidx = blockIdx.y, mh = blockIdx.z;
    const int w = threadIdx.x >> 6, lane = threadIdx.x & 63;
    const f16* __restrict__ Wb = oidx == 0 ? Wqb : oidx == 1 ? Wkb : Wvb;
    const f16* A = hb + (size_t)slab * ND128;

    h8 bfr[2][4];
#pragma unroll
    for (int nt = 0; nt < 2; ++nt)
#pragma unroll
        for (int kb = 0; kb < 4; ++kb)
            bfr[nt][kb] = *(const h8*)(Wb + (size_t)(((2 * w + nt) * 4 + kb) * 64 + lane) * 8);

    f4 acc[4][2];
    f4 zero = {0.f, 0.f, 0.f, 0.f};
#pragma unroll
    for (int m = 0; m < 4; ++m) { acc[m][0] = zero; acc[m][1] = zero; }

#pragma unroll
    for (int m = 0; m < 4; ++m) {
        int mg = mh * 4 + m;
#pragma unroll
        for (int kb = 0; kb < 4; ++kb) {
            h8 a = *(const h8*)(A + (size_t)((kb * 8 + mg) * 64 + lane) * 8);
            acc[m][0] = __builtin_amdgcn_mfma_f32_16x16x32_f16(bfr[0][kb], a, acc[m][0], 0, 0, 0);
            acc[m][1] = __builtin_amdgcn_mfma_f32_16x16x32_f16(bfr[1][kb], a, acc[m][1], 0, 0, 0);
        }
    }

    const int rl = lane & 15, quad = lane >> 4;
    if (oidx == 0) {
#pragma unroll
        for (int m = 0; m < 4; ++m) {
            int gr = slab * 128 + (mh * 4 + m) * 16 + rl;
            if (gr < N) {
#pragma unroll
                for (int nt = 0; nt < 2; ++nt) {
                    h4 o;
                    o[0] = (f16)acc[m][nt][0]; o[1] = (f16)acc[m][nt][1];
                    o[2] = (f16)acc[m][nt][2]; o[3] = (f16)acc[m][nt][3];
                    *(h4*)(Qb + (size_t)gr * 128 + w * 32 + nt * 16 + quad * 4) = o;
                }
            }
        }
    } else {
        const int voff = (oidx == 2) ? 128 : 0;
#pragma unroll
        for (int m = 0; m < 4; ++m) {
            int gr = slab * 128 + (mh * 4 + m) * 16 + rl;
            if (gr < N) {
#pragma unroll
                for (int nt = 0; nt < 2; ++nt) {
                    unsigned pk = fp8_pack4(acc[m][nt][0], acc[m][nt][1],
                                            acc[m][nt][2], acc[m][nt][3]);
                    *(unsigned*)(KV8 + (size_t)gr * 256 + voff + w * 32 + nt * 16 + quad * 4) = pk;
                }
            }
        }
    }
}

// --- scan part A: per-block sums ------------------------------------------
__global__ __launch_bounds__(256) void k_scanA(
    const int* __restrict__ cnt, int* __restrict__ bsum, int N)
{
    const int t = threadIdx.x;
    int base = blockIdx.x * 2048 + t * 8;
    int s = 0;
#pragma unroll
    for (int j = 0; j < 8; ++j) {
        int idx = base + j;
        if (idx < N) s += cnt[idx];
    }
#pragma unroll
    for (int off = 32; off; off >>= 1) s += __shfl_down(s, off, 64);
    __shared__ int ws4[4];
    if ((t & 63) == 0) ws4[t >> 6] = s;
    __syncthreads();
    if (t == 0) bsum[blockIdx.x] = ws4[0] + ws4[1] + ws4[2] + ws4[3];
}

// --- scan part C: finalize rowptr + cursor --------------------------------
__global__ __launch_bounds__(256) void k_scanC(
    const int* __restrict__ cnt, const int* __restrict__ bsum,
    int* __restrict__ rowptr, int* __restrict__ cursor, int N, int nsb)
{
    const int t = threadIdx.x, b = blockIdx.x;
    __shared__ int sboff;
    if (t == 0) {
        int r = 0;
        for (int i2 = 0; i2 < b; ++i2) r += bsum[i2];
        sboff = r;
    }
    if (t == 64 && b == nsb - 1) {
        int r = 0;
        for (int i2 = 0; i2 < nsb; ++i2) r += bsum[i2];
        rowptr[N] = r;
    }
    int base = b * 2048 + t * 8;
    int loc[8];
    int s = 0;
#pragma unroll
    for (int j = 0; j < 8; ++j) {
        int idx = base + j;
        loc[j] = (idx < N) ? cnt[idx] : 0;
        s += loc[j];
    }
    __shared__ int part[256];
    part[t] = s;
    __syncthreads();
    for (int off = 1; off < 256; off <<= 1) {
        int v = (t >= off) ? part[t - off] : 0;
        __syncthreads();
        part[t] += v;
        __syncthreads();
    }
    int run = sboff + (t ? part[t - 1] : 0);
#pragma unroll
    for (int j = 0; j < 8; ++j) {
        int idx = base + j;
        if (idx < N) { rowptr[idx] = run; cursor[idx] = run; run += loc[j]; }
    }
}

// --- scatter edges into CSR ------------------------------------------------
__global__ __launch_bounds__(256) void k_scatter(
    const int* __restrict__ src, const int* __restrict__ dst,
    int* __restrict__ cursor, int* __restrict__ csr_src, int E)
{
    int e = blockIdx.x * 256 + threadIdx.x;
    if (e < E) {
        int pos = atomicAdd(&cursor[dst[e]], 1);
        csr_src[pos] = src[e];
    }
}

// --- attention: one wave per node, lane owns channels (2l, 2l+1). ----------
// fp8 K/V (2B/lane/row each), HW cvt decode, DPP wsum8, exp2, f32 accum.
__global__ __launch_bounds__(256) void k_attn(
    const f16* __restrict__ Qb, const unsigned char* __restrict__ KV8,
    const int* __restrict__ rowptr, const int* __restrict__ csr_src,
    f16* __restrict__ attnf, int N)
{
    const int node = blockIdx.x * 4 + (threadIdx.x >> 6);
    const int lane = threadIdx.x & 63;
    if (node >= N) return;
    const int beg = rowptr[node], end = rowptr[node + 1];

    float qx, qy;
    {
        h2 q2 = ((const h2*)(Qb + (size_t)node * 128))[lane];
        const float SCL = 0.25f * 1.44269504f;
        qx = (float)q2[0] * SCL;
        qy = (float)q2[1] * SCL;
    }
    const float CLP = 5.f * 1.44269504f;

    float axA = 0.f, ayA = 0.f, axB = 0.f, ayB = 0.f, zA = 0.f, zB = 0.f;
    int i = beg;
    for (; i + 3 < end; i += 4) {
        int s0 = csr_src[i], s1 = csr_src[i + 1];
        int s2 = csr_src[i + 2], s3 = csr_src[i + 3];
        unsigned k0 = *(const unsigned short*)(KV8 + (size_t)s0 * 256 + 2 * lane);
        unsigned k1 = *(const unsigned short*)(KV8 + (size_t)s1 * 256 + 2 * lane);
        unsigned k2 = *(const unsigned short*)(KV8 + (size_t)s2 * 256 + 2 * lane);
        unsigned k3 = *(const unsigned short*)(KV8 + (size_t)s3 * 256 + 2 * lane);
        unsigned v0 = *(const unsigned short*)(KV8 + (size_t)s0 * 256 + 128 + 2 * lane);
        unsigned v1 = *(const unsigned short*)(KV8 + (size_t)s1 * 256 + 128 + 2 * lane);
        unsigned v2 = *(const unsigned short*)(KV8 + (size_t)s2 * 256 + 128 + 2 * lane);
        unsigned v3 = *(const unsigned short*)(KV8 + (size_t)s3 * 256 + 128 + 2 * lane);
        ff2 kf0 = fp8x2_dec(k0), kf1 = fp8x2_dec(k1);
        ff2 kf2 = fp8x2_dec(k2), kf3 = fp8x2_dec(k3);
        float p0 = fmaf(qx, kf0.x, qy * kf0.y);
        float p1 = fmaf(qx, kf1.x, qy * kf1.y);
        float p2 = fmaf(qx, kf2.x, qy * kf2.y);
        float p3 = fmaf(qx, kf3.x, qy * kf3.y);
        p0 = wsum8(p0); p1 = wsum8(p1); p2 = wsum8(p2); p3 = wsum8(p3);
        float sc0 = fast_exp2(fminf(fmaxf(p0, -CLP), CLP));
        float sc1 = fast_exp2(fminf(fmaxf(p1, -CLP), CLP));
        float sc2 = fast_exp2(fminf(fmaxf(p2, -CLP), CLP));
        float sc3 = fast_exp2(fminf(fmaxf(p3, -CLP), CLP));
        ff2 vf0 = fp8x2_dec(v0), vf1 = fp8x2_dec(v1);
        ff2 vf2 = fp8x2_dec(v2), vf3 = fp8x2_dec(v3);
        axA = fmaf(vf0.x, sc0, axA); ayA = fmaf(vf0.y, sc0, ayA);
        axB = fmaf(vf1.x, sc1, axB); ayB = fmaf(vf1.y, sc1, ayB);
        axA = fmaf(vf2.x, sc2, axA); ayA = fmaf(vf2.y, sc2, ayA);
        axB = fmaf(vf3.x, sc3, axB); ayB = fmaf(vf3.y, sc3, ayB);
        zA += sc0 + sc2; zB += sc1 + sc3;
    }
    for (; i < end; ++i) {
        int s0 = csr_src[i];
        unsigned k0 = *(const unsigned short*)(KV8 + (size_t)s0 * 256 + 2 * lane);
        unsigned v0 = *(const unsigned short*)(KV8 + (size_t)s0 * 256 + 128 + 2 * lane);
        ff2 kf0 = fp8x2_dec(k0);
        float p0 = fmaf(qx, kf0.x, qy * kf0.y);
        p0 = wsum8(p0);
        float sc0 = fast_exp2(fminf(fmaxf(p0, -CLP), CLP));
        ff2 vf0 = fp8x2_dec(v0);
        axA = fmaf(vf0.x, sc0, axA); ayA = fmaf(vf0.y, sc0, ayA);
        zA += sc0;
    }
    float inv = 1.f / (zA + zB);
    h2 o2;
    o2[0] = (f16)((axA + axB) * inv);
    o2[1] = (f16)((ayA + ayB) * inv);
    int slab = node >> 7, m = (node >> 4) & 7, lr = node & 15;
    int kb = lane >> 4, quad2 = (lane & 15) >> 2, j = (lane & 3) * 2;
    *(h2*)(attnf + (size_t)slab * ND128 +
           (size_t)(((kb * 8 + m) * 64 + lr + 16 * quad2) * 8 + j)) = o2;
}

// ===========================================================================
// k_backc (cooperative, hand barrier): S5 oproj / S6 fold1 / S7 ffn1 /
// S8 ffn2 / S9 bn2-apply.  Never calls cg sync.
// ===========================================================================
__global__ __launch_bounds__(256) void k_backc(
    const f16* __restrict__ attnf, const f16* __restrict__ Wob,
    const float* __restrict__ h, const float* __restrict__ bO,
    f16* __restrict__ t1b, float* __restrict__ bn,
    const float* __restrict__ g1, const float* __restrict__ bb1,
    const float* __restrict__ W1, const float* __restrict__ b1,
    f16* __restrict__ W1b, float* __restrict__ badj,
    float* __restrict__ sfold, float* __restrict__ bfold,
    f16* __restrict__ ub, const f16* __restrict__ W2b,
    const float* __restrict__ b2, float* __restrict__ out,
    const float* __restrict__ g2, const float* __restrict__ bb2,
    int* __restrict__ gcnt, int N, int slabs)
{
    const int tid = threadIdx.x;
    const int G = gridDim.x;
    const int w = tid >> 6, lane = tid & 63;
    const int rl = lane & 15, quad = lane >> 4;
    __shared__ float csum[128], csq[128], sS[128], sB[128];
    __shared__ float red[128];

    // ---- S5: oproj + BN1 sums ----
    {
        h8 bfr[2][4];
#pragma unroll
        for (int nt = 0; nt < 2; ++nt)
#pragma unroll
            for (int kb = 0; kb < 4; ++kb)
                bfr[nt][kb] = *(const h8*)(Wob + (size_t)(((2 * w + nt) * 4 + kb) * 64 + lane) * 8);
        float4 bo[2];
#pragma unroll
        for (int nt = 0; nt < 2; ++nt)
            bo[nt] = *(const float4*)(bO + w * 32 + nt * 16 + quad * 4);

        for (int u = blockIdx.x; u < slabs * 2; u += G) {
            const int slab = u >> 1, mh = u & 1;
            if (tid < 128) { csum[tid] = 0.f; csq[tid] = 0.f; }
            __syncthreads();
            const f16* A = attnf + (size_t)slab * ND128;

            f4 acc[4][2];
            f4 zero = {0.f, 0.f, 0.f, 0.f};
#pragma unroll
            for (int m = 0; m < 4; ++m) { acc[m][0] = zero; acc[m][1] = zero; }
#pragma unroll
            for (int m = 0; m < 4; ++m) {
                int mg = mh * 4 + m;
#pragma unroll
                for (int kb = 0; kb < 4; ++kb) {
                    h8 a = *(const h8*)(A + (size_t)((kb * 8 + mg) * 64 + lane) * 8);
                    acc[m][0] = __builtin_amdgcn_mfma_f32_16x16x32_f16(bfr[0][kb], a, acc[m][0], 0, 0, 0);
                    acc[m][1] = __builtin_amdgcn_mfma_f32_16x16x32_f16(bfr[1][kb], a, acc[m][1], 0, 0, 0);
                }
            }
            float pcs[2][4], pcq[2][4];
#pragma unroll
            for (int nt = 0; nt < 2; ++nt)
#pragma unroll
                for (int r = 0; r < 4; ++r) { pcs[nt][r] = 0.f; pcq[nt][r] = 0.f; }
#pragma unroll
            for (int m = 0; m < 4; ++m) {
                int mg = mh * 4 + m;
                int gr = slab * 128 + mg * 16 + rl;
                if (gr < N) {
#pragma unroll
                    for (int nt = 0; nt < 2; ++nt) {
                        int col0 = w * 32 + nt * 16 + quad * 4;
                        float4 hv = *(const float4*)(h + (size_t)gr * 128 + col0);
                        float v0 = acc[m][nt][0] + hv.x + bo[nt].x;
                        float v1 = acc[m][nt][1] + hv.y + bo[nt].y;
                        float v2 = acc[m][nt][2] + hv.z + bo[nt].z;
                        float v3 = acc[m][nt][3] + hv.w + bo[nt].w;
                        h4 o; o[0] = (f16)v0; o[1] = (f16)v1; o[2] = (f16)v2; o[3] = (f16)v3;
                        *(h4*)(t1b + (size_t)slab * ND128 +
                               (size_t)(((w * 8 + mg) * 64 + (nt * 2 + (quad >> 1)) * 16 + rl) * 8 +
                                        (quad & 1) * 4)) = o;
                        pcs[nt][0] += v0; pcq[nt][0] += v0 * v0;
                        pcs[nt][1] += v1; pcq[nt][1] += v1 * v1;
                        pcs[nt][2] += v2; pcq[nt][2] += v2 * v2;
                        pcs[nt][3] += v3; pcq[nt][3] += v3 * v3;
                    }
                }
            }
#pragma unroll
            for (int nt = 0; nt < 2; ++nt)
#pragma unroll
                for (int r = 0; r < 4; ++r) {
                    float s = pcs[nt][r], q = pcq[nt][r];
                    s += __shfl_xor(s, 8, 16); q += __shfl_xor(q, 8, 16);
                    s += __shfl_xor(s, 4, 16); q += __shfl_xor(q, 4, 16);
                    s += __shfl_xor(s, 2, 16); q += __shfl_xor(q, 2, 16);
                    s += __shfl_xor(s, 1, 16); q += __shfl_xor(q, 1, 16);
                    if (rl == 0) {
                        int cl = w * 32 + nt * 16 + quad * 4 + r;
                        atomicAdd(&csum[cl], s);
                        atomicAdd(&csq[cl], q);
                    }
                }
            __syncthreads();
            if (tid < 128) {
                atomicAdd(bn + tid, csum[tid]);
                atomicAdd(bn + 128 + tid, csq[tid]);
            }
            __syncthreads();
        }
    }
    gbar(gcnt, 1);

    // ---- S6: fold BN1 into W1/bias (256 row units) ----
    for (int u = blockIdx.x; u < 256; u += G) {
        const int o = u;
        if (tid < 128) {
            const int i = tid;
            float invN = 1.f / (float)N;
            float mu = bn[i] * invN;
            float var = bn[128 + i] * invN - mu * mu;
            float s = g1[i] * rsqrtf(var + 1e-5f);
            float bb = bb1[i] - mu * s;
            if (o == 0) { sfold[i] = s; bfold[i] = bb; }
            float wv = W1[(size_t)o * 128 + i];
            red[i] = wv * bb;
            const int nt = o >> 4, lanelow = o & 15;
            const int kb = i >> 5, qq = (i >> 3) & 3, j = i & 7;
            W1b[(size_t)(((nt * 4 + kb) * 64 + lanelow + 16 * qq) * 8 + j)] = (f16)(wv * s);
        }
        __syncthreads();
        for (int off = 64; off; off >>= 1) {
            if (tid < off) red[tid] += red[tid + off];
            __syncthreads();
        }
        if (tid == 0) badj[o] = b1[o] + red[0];
        __syncthreads();
    }
    gbar(gcnt, 2);

    // ---- S7: FFN1 ----
    for (int u = blockIdx.x; u < slabs * 4; u += G) {
        const int slab = u >> 2, ch = (u >> 1) & 1, mh = u & 1;
        const f16* A = t1b + (size_t)slab * ND128;

        h8 bfr[2][4];
#pragma unroll
        for (int nt = 0; nt < 2; ++nt)
#pragma unroll
            for (int kb = 0; kb < 4; ++kb) {
                int ntg = ch * 8 + 2 * w + nt;
                bfr[nt][kb] = *(const h8*)(W1b + (size_t)((ntg * 4 + kb) * 64 + lane) * 8);
            }

        f4 acc[4][2];
        f4 zero = {0.f, 0.f, 0.f, 0.f};
#pragma unroll
        for (int m = 0; m < 4; ++m) { acc[m][0] = zero; acc[m][1] = zero; }
#pragma unroll
        for (int m = 0; m < 4; ++m) {
            int mg = mh * 4 + m;
#pragma unroll
            for (int kb = 0; kb < 4; ++kb) {
                h8 a = *(const h8*)(A + (size_t)((kb * 8 + mg) * 64 + lane) * 8);
                acc[m][0] = __builtin_amdgcn_mfma_f32_16x16x32_f16(bfr[0][kb], a, acc[m][0], 0, 0, 0);
                acc[m][1] = __builtin_amdgcn_mfma_f32_16x16x32_f16(bfr[1][kb], a, acc[m][1], 0, 0, 0);
            }
        }
        const int kbu = ch * 4 + w;
        float4 ba[2];
#pragma unroll
        for (int nt = 0; nt < 2; ++nt)
            ba[nt] = *(const float4*)(badj + ch * 128 + w * 32 + nt * 16 + quad * 4);
#pragma unroll
        for (int m = 0; m < 4; ++m) {
            int mg = mh * 4 + m;
            int gr = slab * 128 + mg * 16 + rl;
            if (gr < N) {
#pragma unroll
                for (int nt = 0; nt < 2; ++nt) {
                    h4 o;
                    o[0] = (f16)fmaxf(acc[m][nt][0] + ba[nt].x, 0.f);
                    o[1] = (f16)fmaxf(acc[m][nt][1] + ba[nt].y, 0.f);
                    o[2] = (f16)fmaxf(acc[m][nt][2] + ba[nt].z, 0.f);
                    o[3] = (f16)fmaxf(acc[m][nt][3] + ba[nt].w, 0.f);
                    *(h4*)(ub + (size_t)slab * 32768 +
                           (size_t)(((kbu * 8 + mg) * 64 + (nt * 2 + (quad >> 1)) * 16 + rl) * 8 +
                                    (quad & 1) * 4)) = o;
                }
            }
        }
    }
    gbar(gcnt, 3);

    // ---- S8: FFN2 + BN2 sums ----
    {
        h8 bfr[2][8];
#pragma unroll
        for (int nt = 0; nt < 2; ++nt)
#pragma unroll
            for (int kb = 0; kb < 8; ++kb)
                bfr[nt][kb] = *(const h8*)(W2b + (size_t)(((2 * w + nt) * 8 + kb) * 64 + lane) * 8);
        if (tid < 128) { sS[tid] = sfold[tid]; sB[tid] = bfold[tid] + b2[tid]; }
        __syncthreads();

        for (int u = blockIdx.x; u < slabs * 2; u += G) {
            const int slab = u >> 1, mh = u & 1;
            if (tid < 128) { csum[tid] = 0.f; csq[tid] = 0.f; }
            __syncthreads();
            const f16* A = ub + (size_t)slab * 32768;
            const f16* T1 = t1b + (size_t)slab * ND128;

            f4 acc[4][2];
            f4 zero = {0.f, 0.f, 0.f, 0.f};
#pragma unroll
            for (int m = 0; m < 4; ++m) { acc[m][0] = zero; acc[m][1] = zero; }
#pragma unroll
            for (int m = 0; m < 4; ++m) {
                int mg = mh * 4 + m;
#pragma unroll
                for (int kb = 0; kb < 8; ++kb) {
                    h8 a = *(const h8*)(A + (size_t)((kb * 8 + mg) * 64 + lane) * 8);
                    acc[m][0] = __builtin_amdgcn_mfma_f32_16x16x32_f16(bfr[0][kb], a, acc[m][0], 0, 0, 0);
                    acc[m][1] = __builtin_amdgcn_mfma_f32_16x16x32_f16(bfr[1][kb], a, acc[m][1], 0, 0, 0);
                }
            }
            float pcs[2][4], pcq[2][4];
#pragma unroll
            for (int nt = 0; nt < 2; ++nt)
#pragma unroll
                for (int r = 0; r < 4; ++r) { pcs[nt][r] = 0.f; pcq[nt][r] = 0.f; }
#pragma unroll
            for (int m = 0; m < 4; ++m) {
                int mg = mh * 4 + m;
                int gr = slab * 128 + mg * 16 + rl;
                if (gr < N) {
#pragma unroll
                    for (int nt = 0; nt < 2; ++nt) {
                        int col0 = w * 32 + nt * 16 + quad * 4;
                        h4 t1v = *(const h4*)(T1 +
                            (size_t)(((w * 8 + mg) * 64 + (nt * 2 + (quad >> 1)) * 16 + rl) * 8 +
                                     (quad & 1) * 4));
                        float4 ss = *(const float4*)&sS[col0];
                        float4 sb = *(const float4*)&sB[col0];
                        float4 o;
                        o.x = acc[m][nt][0] + fmaf(ss.x, (float)t1v[0], sb.x);
                        o.y = acc[m][nt][1] + fmaf(ss.y, (float)t1v[1], sb.y);
                        o.z = acc[m][nt][2] + fmaf(ss.z, (float)t1v[2], sb.z);
                        o.w = acc[m][nt][3] + fmaf(ss.w, (float)t1v[3], sb.w);
                        *(float4*)(out + (size_t)gr * 128 + col0) = o;
                        pcs[nt][0] += o.x; pcq[nt][0] += o.x * o.x;
                        pcs[nt][1] += o.y; pcq[nt][1] += o.y * o.y;
                        pcs[nt][2] += o.z; pcq[nt][2] += o.z * o.z;
                        pcs[nt][3] += o.w; pcq[nt][3] += o.w * o.w;
                    }
                }
            }
#pragma unroll
            for (int nt = 0; nt < 2; ++nt)
#pragma unroll
                for (int r = 0; r < 4; ++r) {
                    float s = pcs[nt][r], q = pcq[nt][r];
                    s += __shfl_xor(s, 8, 16); q += __shfl_xor(q, 8, 16);
                    s += __shfl_xor(s, 4, 16); q += __shfl_xor(q, 4, 16);
                    s += __shfl_xor(s, 2, 16); q += __shfl_xor(q, 2, 16);
                    s += __shfl_xor(s, 1, 16); q += __shfl_xor(q, 1, 16);
                    if (rl == 0) {
                        int cl = w * 32 + nt * 16 + quad * 4 + r;
                        atomicAdd(&csum[cl], s);
                        atomicAdd(&csq[cl], q);
                    }
                }
            __syncthreads();
            if (tid < 128) {
                atomicAdd(bn + 256 + tid, csum[tid]);
                atomicAdd(bn + 384 + tid, csq[tid]);
            }
            __syncthreads();
        }
    }
    gbar(gcnt, 4);

    // ---- S9: BN2 normalize in place ----
    if (tid < 128) {
        float invN = 1.f / (float)N;
        float mu = bn[256 + tid] * invN;
        float var = bn[384 + tid] * invN - mu * mu;
        float scl = g2[tid] * rsqrtf(var + 1e-5f);
        sS[tid] = scl;
        sB[tid] = bb2[tid] - mu * scl;
    }
    __syncthreads();
    const size_t total = (size_t)N * 32;
    const int U9 = (int)((total + 255) / 256);
    for (int u = blockIdx.x; u < U9; u += G) {
        size_t idx = (size_t)u * 256 + tid;
        if (idx < total) {
            int c0 = (int)((idx * 4) & 127);
            float4 v = *(const float4*)(out + idx * 4);
            v.x = fmaf(v.x, sS[c0 + 0], sB[c0 + 0]);
            v.y = fmaf(v.y, sS[c0 + 1], sB[c0 + 1]);
            v.z = fmaf(v.z, sS[c0 + 2], sB[c0 + 2]);
            v.w = fmaf(v.w, sS[c0 + 3], sB[c0 + 3]);
            *(float4*)(out + idx * 4) = v;
        }
    }
}

extern "C" void kernel_launch(void* const* d_in, const int* in_sizes, int n_in,
                              void* d_out, int out_size, void* d_ws, size_t ws_size,
                              hipStream_t stream)
{
    const float* h   = (const float*)d_in[0];
    const int*   src = (const int*)d_in[1];
    const int*   dst = (const int*)d_in[2];
    const float* WQ  = (const float*)d_in[3];
    const float* WK  = (const float*)d_in[4];
    const float* WV  = (const float*)d_in[5];
    const float* WO  = (const float*)d_in[6];
    const float* bO  = (const float*)d_in[7];
    const float* W1  = (const float*)d_in[8];
    const float* b1  = (const float*)d_in[9];
    const float* W2  = (const float*)d_in[10];
    const float* b2  = (const float*)d_in[11];
    const float* g1  = (const float*)d_in[12];
    const float* bb1 = (const float*)d_in[13];
    const float* g2  = (const float*)d_in[14];
    const float* bb2 = (const float*)d_in[15];
    float* out = (float*)d_out;

    int N = in_sizes[0] / 128;
    int E = in_sizes[1];
    int slabs = (N + 127) / 128;
    int nsb = (N + 2047) / 2048;               // scan blocks (~25)
    int nhb = (E + 255) / 256;                 // edge blocks (~2500)
    const size_t B1 = (size_t)slabs * 32768;   // bytes of one f16 N_pad x 128 buffer

    char* Wp = (char*)d_ws;
    f16* hb  = (f16*)Wp;                       // becomes attnf after attn
    f16* Qb  = (f16*)(Wp + B1);                // B1
    unsigned char* KV8 = (unsigned char*)(Wp + 2 * B1);  // B1 (fp8 K|V 256B rows)
    f16* ub  = (f16*)(Wp + B1);                // 2*B1, overlays Qb+KV8 after attn
    f16* t1b = (f16*)(Wp + 3 * B1);            // B1
    const size_t base = 4 * B1;
    f16* Wqb = (f16*)(Wp + base);
    f16* Wkb = (f16*)(Wp + base + 32768);
    f16* Wvb = (f16*)(Wp + base + 65536);
    f16* Wob = (f16*)(Wp + base + 98304);
    f16* W1b = (f16*)(Wp + base + 131072);
    f16* W2b = (f16*)(Wp + base + 196608);
    float* badj  = (float*)(Wp + base + 262144);
    float* sfold = (float*)(Wp + base + 263168);
    float* bfold = (float*)(Wp + base + 263680);
    float* bn    = (float*)(Wp + base + 264192);     // 512 floats (memset)
    int* gcnt    = (int*)(Wp + base + 266240);       // barrier counter (memset)
    int* bsum    = (int*)(Wp + base + 266496);       // 64 ints
    int* cursor  = (int*)(Wp + base + 266752);       // N ints (memset)
    int* rowptr  = (int*)(Wp + base + 266752 + (size_t)N * 4);
    int* csr     = (int*)(Wp + base + 266752 + (size_t)N * 8 + 8);

    static int ncu = 0, nbk = 0;
    if (ncu == 0) {
        int dev = 0;
        hipGetDevice(&dev);
        hipDeviceGetAttribute(&ncu, hipDeviceAttributeMultiprocessorCount, dev);
        hipOccupancyMaxActiveBlocksPerMultiprocessor(&nbk, k_backc, 256, 0);
        if (ncu <= 0) ncu = 256;
        if (nbk <= 0) nbk = 1;
    }
    int G2 = ncu * nbk;
    if (G2 > slabs * 4) G2 = slabs * 4;

    // zero bn(2048) + gcnt(256) + bsum(256) + cursor(N*4) in one memset
    hipMemsetAsync(Wp + base + 264192, 0, 2560 + (size_t)N * 4, stream);
    k_prep_hist<<<nhb + slabs * 2, 256, 0, stream>>>(
        h, hb, WQ, WK, WV, WO, W2, Wqb, Wkb, Wvb, Wob, W2b, cursor, dst, N, E, nhb);
    k_qkv<<<dim3(slabs, 3, 2), 256, 0, stream>>>(hb, Wqb, Wkb, Wvb, Qb, KV8, N);
    k_scanA<<<nsb, 256, 0, stream>>>(cursor, bsum, N);
    k_scanC<<<nsb, 256, 0, stream>>>(cursor, bsum, rowptr, cursor, N, nsb);
    k_scatter<<<nhb, 256, 0, stream>>>(src, dst, cursor, csr, E);
    k_attn<<<(N + 3) / 4, 256, 0, stream>>>(Qb, KV8, rowptr, csr, hb, N);
    {
        void* a2[] = {(void*)&hb, (void*)&Wob, (void*)&h, (void*)&bO, (void*)&t1b,
                      (void*)&bn, (void*)&g1, (void*)&bb1, (void*)&W1, (void*)&b1,
                      (void*)&W1b, (void*)&badj, (void*)&sfold, (void*)&bfold,
                      (void*)&ub, (void*)&W2b, (void*)&b2, (void*)&out,
                      (void*)&g2, (void*)&bb2, (void*)&gcnt, (void*)&N, (void*)&slabs};
        hipLaunchCooperativeKernel((void*)k_backc, dim3(G2), dim3(256), a2, 0, stream);
    }
}

// Round 6
// 341.650 us; speedup vs baseline: 1.9501x; 1.6422x over previous
//
#include <hip/hip_runtime.h>
#include <math.h>

// ---------------------------------------------------------------------------
// GraphTransformerLayer N=50000, E=640000, D=128, H=8, DH=16  (gfx950)
// Round 17: plain dispatches only (R16 proved boundaries cost ~2-3us; all
// grid-wide-sync fusion is dead: ~100us/barrier regardless of impl).
//  - oproj: m-split x4 (1564 blocks, kills grid-quantization tail) and
//    residual read from hb f16 frags (same addressing as t1b write) instead
//    of fp32 h. attnf gets its own buffer so hb survives attn.
//  - ffn2: m-split x4.
//  - front + attn (fp8 KV + DPP/exp2 math) + fold1 + ffn1 + bn2 = R16.
//
// Fragment order for an MxK slab (M=128, K=KB*32):
//   elem index = ((kb*8 + mtile)*64 + lane)*8 + j
//   row = mtile*16 + (lane&15),  col = kb*32 + (lane>>4)*8 + j
// Swapped-operand MFMA: mfma(Wfrag, hfrag) -> C^T: row = m*16+(lane&15),
// cols = w*32+nt*16+quad*4+{0..3} contiguous.
// ---------------------------------------------------------------------------

#define ND128 16384
typedef _Float16 f16;
typedef __attribute__((ext_vector_type(8))) _Float16 h8;
typedef __attribute__((ext_vector_type(4))) _Float16 h4;
typedef __attribute__((ext_vector_type(2))) _Float16 h2;
typedef __attribute__((ext_vector_type(4))) float f4;
typedef __attribute__((ext_vector_type(2))) float ff2;

__device__ __forceinline__ float fast_exp2(float x) {
#if __has_builtin(__builtin_amdgcn_exp2f)
    return __builtin_amdgcn_exp2f(x);
#else
    return exp2f(x);
#endif
}

template <int CTRL>
__device__ __forceinline__ float dppadd(float x) {
    int t = __builtin_amdgcn_update_dpp(0, __float_as_int(x), CTRL, 0xF, 0xF, false);
    return x + __int_as_float(t);
}
__device__ __forceinline__ float wsum8(float p) {
    p = dppadd<0xB1>(p);    // quad_perm [1,0,3,2]
    p = dppadd<0x4E>(p);    // quad_perm [2,3,0,1]
    p = dppadd<0x141>(p);   // row_half_mirror
    return p;
}

__device__ __forceinline__ ff2 fp8x2_dec(unsigned v) {
#if __has_builtin(__builtin_amdgcn_cvt_pk_f32_fp8)
    return __builtin_amdgcn_cvt_pk_f32_fp8((int)v, false);
#else
    ff2 r;
    unsigned b0 = v & 0xffu, b1 = (v >> 8) & 0xffu;
    {
        unsigned e = (b0 >> 3) & 15u, m = b0 & 7u;
        float x = e ? __uint_as_float(((e + 120u) << 23) | (m << 20)) : (float)m * 0.001953125f;
        r.x = (b0 & 0x80u) ? -x : x;
    }
    {
        unsigned e = (b1 >> 3) & 15u, m = b1 & 7u;
        float x = e ? __uint_as_float(((e + 120u) << 23) | (m << 20)) : (float)m * 0.001953125f;
        r.y = (b1 & 0x80u) ? -x : x;
    }
    return r;
#endif
}

#if !__has_builtin(__builtin_amdgcn_cvt_pk_fp8_f32)
__device__ __forceinline__ unsigned char fp8_1(float f) {
    float a = fabsf(f);
    unsigned sg = (__float_as_uint(f) >> 31) << 7;
    if (a >= 448.f) return (unsigned char)(sg | 0x7E);
    if (a < 0.0009765625f) return (unsigned char)sg;
    int E; float m = frexpf(a, &E);
    if (E - 1 < -6) {
        int q = (int)rintf(a * 512.f);
        if (q > 7) return (unsigned char)(sg | 0x08);
        return (unsigned char)(sg | q);
    }
    int q = (int)rintf(m * 16.f);
    if (q == 16) { q = 8; E += 1; }
    int Ef = E - 1 + 7;
    if (Ef > 15) return (unsigned char)(sg | 0x7E);
    return (unsigned char)(sg | (Ef << 3) | (q - 8));
}
#endif

__device__ __forceinline__ unsigned fp8_pack4(float a0, float a1, float a2, float a3) {
#if __has_builtin(__builtin_amdgcn_cvt_pk_fp8_f32)
    int pk = __builtin_amdgcn_cvt_pk_fp8_f32(a0, a1, 0, false);
    pk = __builtin_amdgcn_cvt_pk_fp8_f32(a2, a3, pk, true);
    return (unsigned)pk;
#else
    return (unsigned)fp8_1(a0) | ((unsigned)fp8_1(a1) << 8) |
           ((unsigned)fp8_1(a2) << 16) | ((unsigned)fp8_1(a3) << 24);
#endif
}

// --- K1: hist (blocks [0,nhb)) UNION prep (blocks [nhb, nhb+slabs*2)). ----
__global__ __launch_bounds__(256) void k_prep_hist(
    const float* __restrict__ h, f16* __restrict__ hb,
    const float* __restrict__ WQ, const float* __restrict__ WK,
    const float* __restrict__ WV, const float* __restrict__ WO,
    const float* __restrict__ W2,
    f16* __restrict__ Wqb, f16* __restrict__ Wkb,
    f16* __restrict__ Wvb, f16* __restrict__ Wob, f16* __restrict__ W2b,
    int* __restrict__ cursor, const int* __restrict__ dst,
    int N, int E, int nhb)
{
    const int tid = threadIdx.x;
    if (blockIdx.x < (unsigned)nhb) {
        int e = blockIdx.x * 256 + tid;
        if (e < E) atomicAdd(&cursor[dst[e]], 1);
        return;
    }
    const int p = blockIdx.x - nhb;
    const int slab = p >> 1, my = p & 1;
#pragma unroll
    for (int it2 = 0; it2 < 4; ++it2) {
        int it = my * 4 + it2;
        int cid = it * 256 + tid;              // 0..2047
        int lane = cid & 63;
        int m = (cid >> 6) & 7;
        int kb = cid >> 9;
        int row = slab * 128 + m * 16 + (lane & 15);
        int col = kb * 32 + (lane >> 4) * 8;
        f16 o8[8];
        if (row < N) {
            const float* pp = h + (size_t)row * 128 + col;
            float4 f0 = *(const float4*)pp;
            float4 f1 = *(const float4*)(pp + 4);
            o8[0] = (f16)f0.x; o8[1] = (f16)f0.y; o8[2] = (f16)f0.z; o8[3] = (f16)f0.w;
            o8[4] = (f16)f1.x; o8[5] = (f16)f1.y; o8[6] = (f16)f1.z; o8[7] = (f16)f1.w;
        } else {
#pragma unroll
            for (int j = 0; j < 8; ++j) o8[j] = (f16)0.f;
        }
        *(h8*)(hb + (size_t)slab * ND128 + (size_t)cid * 8) = *(const h8*)o8;
    }
    if (slab < 6 && my == 1) {
        const float* Wsrc; f16* dstw; int K, base;
        if (slab < 4) {
            Wsrc = slab == 0 ? WQ : slab == 1 ? WK : slab == 2 ? WV : WO;
            dstw = slab == 0 ? Wqb : slab == 1 ? Wkb : slab == 2 ? Wvb : Wob;
            K = 128; base = 0;
        } else {
            Wsrc = W2; dstw = W2b; K = 256; base = (slab - 4) * 2048;
        }
#pragma unroll
        for (int it = 0; it < 8; ++it) {
            int cid = base + it * 256 + tid;
            int lane = cid & 63;
            int kb, nt;
            if (K == 128) { kb = (cid >> 6) & 3; nt = cid >> 8; }
            else          { kb = (cid >> 6) & 7; nt = cid >> 9; }
            int row = nt * 16 + (lane & 15);
            int col = kb * 32 + (lane >> 4) * 8;
            const float* pp = Wsrc + (size_t)row * K + col;
            f16 o8[8];
#pragma unroll
            for (int j = 0; j < 8; ++j) o8[j] = (f16)pp[j];
            *(h8*)(dstw + (size_t)cid * 8) = *(const h8*)o8;
        }
    }
}

// --- K2: QKV grid (slabs, 3, 2). Q f16 rows; K/V fp8 in 256B rows of KV8. -
__global__ __launch_bounds__(256) void k_qkv(
    const f16* __restrict__ hb, const f16* __restrict__ Wqb,
    const f16* __restrict__ Wkb, const f16* __restrict__ Wvb,
    f16* __restrict__ Qb, unsigned char* __restrict__ KV8, int N)
{
    const int slab = blockIdx.x, oidx = blockIdx.y, mh = blockIdx.z;
    const int w = threadIdx.x >> 6, lane = threadIdx.x & 63;
    const f16* __restrict__ Wb = oidx == 0 ? Wqb : oidx == 1 ? Wkb : Wvb;
    const f16* A = hb + (size_t)slab * ND128;

    h8 bfr[2][4];
#pragma unroll
    for (int nt = 0; nt < 2; ++nt)
#pragma unroll
        for (int kb = 0; kb < 4; ++kb)
            bfr[nt][kb] = *(const h8*)(Wb + (size_t)(((2 * w + nt) * 4 + kb) * 64 + lane) * 8);

    f4 acc[4][2];
    f4 zero = {0.f, 0.f, 0.f, 0.f};
#pragma unroll
    for (int m = 0; m < 4; ++m) { acc[m][0] = zero; acc[m][1] = zero; }

#pragma unroll
    for (int m = 0; m < 4; ++m) {
        int mg = mh * 4 + m;
#pragma unroll
        for (int kb = 0; kb < 4; ++kb) {
            h8 a = *(const h8*)(A + (size_t)((kb * 8 + mg) * 64 + lane) * 8);
            acc[m][0] = __builtin_amdgcn_mfma_f32_16x16x32_f16(bfr[0][kb], a, acc[m][0], 0, 0, 0);
            acc[m][1] = __builtin_amdgcn_mfma_f32_16x16x32_f16(bfr[1][kb], a, acc[m][1], 0, 0, 0);
        }
    }

    const int rl = lane & 15, quad = lane >> 4;
    if (oidx == 0) {
#pragma unroll
        for (int m = 0; m < 4; ++m) {
            int gr = slab * 128 + (mh * 4 + m) * 16 + rl;
            if (gr < N) {
#pragma unroll
                for (int nt = 0; nt < 2; ++nt) {
                    h4 o;
                    o[0] = (f16)acc[m][nt][0]; o[1] = (f16)acc[m][nt][1];
                    o[2] = (f16)acc[m][nt][2]; o[3] = (f16)acc[m][nt][3];
                    *(h4*)(Qb + (size_t)gr * 128 + w * 32 + nt * 16 + quad * 4) = o;
                }
            }
        }
    } else {
        const int voff = (oidx == 2) ? 128 : 0;
#pragma unroll
        for (int m = 0; m < 4; ++m) {
            int gr = slab * 128 + (mh * 4 + m) * 16 + rl;
            if (gr < N) {
#pragma unroll
                for (int nt = 0; nt < 2; ++nt) {
                    unsigned pk = fp8_pack4(acc[m][nt][0], acc[m][nt][1],
                                            acc[m][nt][2], acc[m][nt][3]);
                    *(unsigned*)(KV8 + (size_t)gr * 256 + voff + w * 32 + nt * 16 + quad * 4) = pk;
                }
            }
        }
    }
}

// --- scan part A ----------------------------------------------------------
__global__ __launch_bounds__(256) void k_scanA(
    const int* __restrict__ cnt, int* __restrict__ bsum, int N)
{
    const int t = threadIdx.x;
    int base = blockIdx.x * 2048 + t * 8;
    int s = 0;
#pragma unroll
    for (int j = 0; j < 8; ++j) {
        int idx = base + j;
        if (idx < N) s += cnt[idx];
    }
#pragma unroll
    for (int off = 32; off; off >>= 1) s += __shfl_down(s, off, 64);
    __shared__ int ws4[4];
    if ((t & 63) == 0) ws4[t >> 6] = s;
    __syncthreads();
    if (t == 0) bsum[blockIdx.x] = ws4[0] + ws4[1] + ws4[2] + ws4[3];
}

// --- scan part C ----------------------------------------------------------
__global__ __launch_bounds__(256) void k_scanC(
    const int* __restrict__ cnt, const int* __restrict__ bsum,
    int* __restrict__ rowptr, int* __restrict__ cursor, int N, int nsb)
{
    const int t = threadIdx.x, b = blockIdx.x;
    __shared__ int sboff;
    if (t == 0) {
        int r = 0;
        for (int i2 = 0; i2 < b; ++i2) r += bsum[i2];
        sboff = r;
    }
    if (t == 64 && b == nsb - 1) {
        int r = 0;
        for (int i2 = 0; i2 < nsb; ++i2) r += bsum[i2];
        rowptr[N] = r;
    }
    int base = b * 2048 + t * 8;
    int loc[8];
    int s = 0;
#pragma unroll
    for (int j = 0; j < 8; ++j) {
        int idx = base + j;
        loc[j] = (idx < N) ? cnt[idx] : 0;
        s += loc[j];
    }
    __shared__ int part[256];
    part[t] = s;
    __syncthreads();
    for (int off = 1; off < 256; off <<= 1) {
        int v = (t >= off) ? part[t - off] : 0;
        __syncthreads();
        part[t] += v;
        __syncthreads();
    }
    int run = sboff + (t ? part[t - 1] : 0);
#pragma unroll
    for (int j = 0; j < 8; ++j) {
        int idx = base + j;
        if (idx < N) { rowptr[idx] = run; cursor[idx] = run; run += loc[j]; }
    }
}

// --- scatter edges into CSR ------------------------------------------------
__global__ __launch_bounds__(256) void k_scatter(
    const int* __restrict__ src, const int* __restrict__ dst,
    int* __restrict__ cursor, int* __restrict__ csr_src, int E)
{
    int e = blockIdx.x * 256 + threadIdx.x;
    if (e < E) {
        int pos = atomicAdd(&cursor[dst[e]], 1);
        csr_src[pos] = src[e];
    }
}

// --- attention: one wave per node, lane owns channels (2l, 2l+1). ----------
__global__ __launch_bounds__(256) void k_attn(
    const f16* __restrict__ Qb, const unsigned char* __restrict__ KV8,
    const int* __restrict__ rowptr, const int* __restrict__ csr_src,
    f16* __restrict__ attnf, int N)
{
    const int node = blockIdx.x * 4 + (threadIdx.x >> 6);
    const int lane = threadIdx.x & 63;
    if (node >= N) return;
    const int beg = rowptr[node], end = rowptr[node + 1];

    float qx, qy;
    {
        h2 q2 = ((const h2*)(Qb + (size_t)node * 128))[lane];
        const float SCL = 0.25f * 1.44269504f;
        qx = (float)q2[0] * SCL;
        qy = (float)q2[1] * SCL;
    }
    const float CLP = 5.f * 1.44269504f;

    float axA = 0.f, ayA = 0.f, axB = 0.f, ayB = 0.f, zA = 0.f, zB = 0.f;
    int i = beg;
    for (; i + 3 < end; i += 4) {
        int s0 = csr_src[i], s1 = csr_src[i + 1];
        int s2 = csr_src[i + 2], s3 = csr_src[i + 3];
        unsigned k0 = *(const unsigned short*)(KV8 + (size_t)s0 * 256 + 2 * lane);
        unsigned k1 = *(const unsigned short*)(KV8 + (size_t)s1 * 256 + 2 * lane);
        unsigned k2 = *(const unsigned short*)(KV8 + (size_t)s2 * 256 + 2 * lane);
        unsigned k3 = *(const unsigned short*)(KV8 + (size_t)s3 * 256 + 2 * lane);
        unsigned v0 = *(const unsigned short*)(KV8 + (size_t)s0 * 256 + 128 + 2 * lane);
        unsigned v1 = *(const unsigned short*)(KV8 + (size_t)s1 * 256 + 128 + 2 * lane);
        unsigned v2 = *(const unsigned short*)(KV8 + (size_t)s2 * 256 + 128 + 2 * lane);
        unsigned v3 = *(const unsigned short*)(KV8 + (size_t)s3 * 256 + 128 + 2 * lane);
        ff2 kf0 = fp8x2_dec(k0), kf1 = fp8x2_dec(k1);
        ff2 kf2 = fp8x2_dec(k2), kf3 = fp8x2_dec(k3);
        float p0 = fmaf(qx, kf0.x, qy * kf0.y);
        float p1 = fmaf(qx, kf1.x, qy * kf1.y);
        float p2 = fmaf(qx, kf2.x, qy * kf2.y);
        float p3 = fmaf(qx, kf3.x, qy * kf3.y);
        p0 = wsum8(p0); p1 = wsum8(p1); p2 = wsum8(p2); p3 = wsum8(p3);
        float sc0 = fast_exp2(fminf(fmaxf(p0, -CLP), CLP));
        float sc1 = fast_exp2(fminf(fmaxf(p1, -CLP), CLP));
        float sc2 = fast_exp2(fminf(fmaxf(p2, -CLP), CLP));
        float sc3 = fast_exp2(fminf(fmaxf(p3, -CLP), CLP));
        ff2 vf0 = fp8x2_dec(v0), vf1 = fp8x2_dec(v1);
        ff2 vf2 = fp8x2_dec(v2), vf3 = fp8x2_dec(v3);
        axA = fmaf(vf0.x, sc0, axA); ayA = fmaf(vf0.y, sc0, ayA);
        axB = fmaf(vf1.x, sc1, axB); ayB = fmaf(vf1.y, sc1, ayB);
        axA = fmaf(vf2.x, sc2, axA); ayA = fmaf(vf2.y, sc2, ayA);
        axB = fmaf(vf3.x, sc3, axB); ayB = fmaf(vf3.y, sc3, ayB);
        zA += sc0 + sc2; zB += sc1 + sc3;
    }
    for (; i < end; ++i) {
        int s0 = csr_src[i];
        unsigned k0 = *(const unsigned short*)(KV8 + (size_t)s0 * 256 + 2 * lane);
        unsigned v0 = *(const unsigned short*)(KV8 + (size_t)s0 * 256 + 128 + 2 * lane);
        ff2 kf0 = fp8x2_dec(k0);
        float p0 = fmaf(qx, kf0.x, qy * kf0.y);
        p0 = wsum8(p0);
        float sc0 = fast_exp2(fminf(fmaxf(p0, -CLP), CLP));
        ff2 vf0 = fp8x2_dec(v0);
        axA = fmaf(vf0.x, sc0, axA); ayA = fmaf(vf0.y, sc0, ayA);
        zA += sc0;
    }
    float inv = 1.f / (zA + zB);
    h2 o2;
    o2[0] = (f16)((axA + axB) * inv);
    o2[1] = (f16)((ayA + ayB) * inv);
    int slab = node >> 7, m = (node >> 4) & 7, lr = node & 15;
    int kb = lane >> 4, quad2 = (lane & 15) >> 2, j = (lane & 3) * 2;
    *(h2*)(attnf + (size_t)slab * ND128 +
           (size_t)(((kb * 8 + m) * 64 + lr + 16 * quad2) * 8 + j)) = o2;
}

// --- O-proj: t1 = attn @ WO^T + h + bO -> f16 frag t1b; BN1 sums. ----------
// grid (slabs, 4): blockIdx.y picks pairs of m-tiles. Residual from hb f16
// frags (same address pattern as the t1b write).
__global__ __launch_bounds__(256) void k_oproj(
    const f16* __restrict__ attnf, const f16* __restrict__ Wob,
    const f16* __restrict__ hbf, const float* __restrict__ bO,
    f16* __restrict__ t1b, float* __restrict__ bn, int N)
{
    __shared__ float csum[128], csq[128];
    const int tid = threadIdx.x, slab = blockIdx.x, mh = blockIdx.y;
    const int w = tid >> 6, lane = tid & 63;
    if (tid < 128) { csum[tid] = 0.f; csq[tid] = 0.f; }
    __syncthreads();
    const f16* A = attnf + (size_t)slab * ND128;
    const f16* HB = hbf + (size_t)slab * ND128;

    h8 bfr[2][4];
#pragma unroll
    for (int nt = 0; nt < 2; ++nt)
#pragma unroll
        for (int kb = 0; kb < 4; ++kb)
            bfr[nt][kb] = *(const h8*)(Wob + (size_t)(((2 * w + nt) * 4 + kb) * 64 + lane) * 8);

    f4 acc[2][2];
    f4 zero = {0.f, 0.f, 0.f, 0.f};
#pragma unroll
    for (int m = 0; m < 2; ++m) { acc[m][0] = zero; acc[m][1] = zero; }
#pragma unroll
    for (int m = 0; m < 2; ++m) {
        int mg = mh * 2 + m;
#pragma unroll
        for (int kb = 0; kb < 4; ++kb) {
            h8 a = *(const h8*)(A + (size_t)((kb * 8 + mg) * 64 + lane) * 8);
            acc[m][0] = __builtin_amdgcn_mfma_f32_16x16x32_f16(bfr[0][kb], a, acc[m][0], 0, 0, 0);
            acc[m][1] = __builtin_amdgcn_mfma_f32_16x16x32_f16(bfr[1][kb], a, acc[m][1], 0, 0, 0);
        }
    }

    const int rl = lane & 15, quad = lane >> 4;
    float4 bo[2];
#pragma unroll
    for (int nt = 0; nt < 2; ++nt)
        bo[nt] = *(const float4*)(bO + w * 32 + nt * 16 + quad * 4);
    float pcs[2][4], pcq[2][4];
#pragma unroll
    for (int nt = 0; nt < 2; ++nt)
#pragma unroll
        for (int r = 0; r < 4; ++r) { pcs[nt][r] = 0.f; pcq[nt][r] = 0.f; }

#pragma unroll
    for (int m = 0; m < 2; ++m) {
        int mg = mh * 2 + m;
        int gr = slab * 128 + mg * 16 + rl;
        if (gr < N) {
#pragma unroll
            for (int nt = 0; nt < 2; ++nt) {
                size_t fidx = (size_t)(((w * 8 + mg) * 64 + (nt * 2 + (quad >> 1)) * 16 + rl) * 8 +
                                       (quad & 1) * 4);
                h4 hv4 = *(const h4*)(HB + fidx);
                float v0 = acc[m][nt][0] + (float)hv4[0] + bo[nt].x;
                float v1 = acc[m][nt][1] + (float)hv4[1] + bo[nt].y;
                float v2 = acc[m][nt][2] + (float)hv4[2] + bo[nt].z;
                float v3 = acc[m][nt][3] + (float)hv4[3] + bo[nt].w;
                h4 o; o[0] = (f16)v0; o[1] = (f16)v1; o[2] = (f16)v2; o[3] = (f16)v3;
                *(h4*)(t1b + (size_t)slab * ND128 + fidx) = o;
                pcs[nt][0] += v0; pcq[nt][0] += v0 * v0;
                pcs[nt][1] += v1; pcq[nt][1] += v1 * v1;
                pcs[nt][2] += v2; pcq[nt][2] += v2 * v2;
                pcs[nt][3] += v3; pcq[nt][3] += v3 * v3;
            }
        }
    }
#pragma unroll
    for (int nt = 0; nt < 2; ++nt)
#pragma unroll
        for (int r = 0; r < 4; ++r) {
            float s = pcs[nt][r], q = pcq[nt][r];
            s += __shfl_xor(s, 8, 16); q += __shfl_xor(q, 8, 16);
            s += __shfl_xor(s, 4, 16); q += __shfl_xor(q, 4, 16);
            s += __shfl_xor(s, 2, 16); q += __shfl_xor(q, 2, 16);
            s += __shfl_xor(s, 1, 16); q += __shfl_xor(q, 1, 16);
            if (rl == 0) {
                int cl = w * 32 + nt * 16 + quad * 4 + r;
                atomicAdd(&csum[cl], s);
                atomicAdd(&csq[cl], q);
            }
        }
    __syncthreads();
    if (tid < 128) {
        atomicAdd(bn + tid, csum[tid]);
        atomicAdd(bn + 128 + tid, csq[tid]);
    }
}

// --- fold BN1 into W1/bias. 256 blocks (one per W1 row). -------------------
__global__ __launch_bounds__(128) void k_fold1(
    const float* __restrict__ bn, const float* __restrict__ g1,
    const float* __restrict__ bb1, const float* __restrict__ W1,
    const float* __restrict__ b1, f16* __restrict__ W1b,
    float* __restrict__ badj, float* __restrict__ sfold,
    float* __restrict__ bfold, int N)
{
    const int o = blockIdx.x, i = threadIdx.x;
    float invN = 1.f / (float)N;
    float mu = bn[i] * invN;
    float var = bn[128 + i] * invN - mu * mu;
    float s = g1[i] * rsqrtf(var + 1e-5f);
    float bb = bb1[i] - mu * s;
    if (o == 0) { sfold[i] = s; bfold[i] = bb; }
    float wv = W1[(size_t)o * 128 + i];
    __shared__ float red[128];
    red[i] = wv * bb;
    const int nt = o >> 4, lanelow = o & 15;
    const int kb = i >> 5, quad = (i >> 3) & 3, j = i & 7;
    W1b[(size_t)(((nt * 4 + kb) * 64 + lanelow + 16 * quad) * 8 + j)] = (f16)(wv * s);
    __syncthreads();
#pragma unroll
    for (int off = 64; off; off >>= 1) {
        if (i < off) red[i] += red[i + off];
        __syncthreads();
    }
    if (i == 0) badj[o] = b1[o] + red[0];
}

// --- FFN1: u = relu(t1b @ W1s^T + badj), f16 frag order (K=256 layout). ----
__global__ __launch_bounds__(256) void k_ffn1(
    const f16* __restrict__ t1b, const f16* __restrict__ W1b,
    const float* __restrict__ badj, f16* __restrict__ ub, int N)
{
    const int slab = blockIdx.x, ch = blockIdx.y, mh = blockIdx.z;
    const int w = threadIdx.x >> 6, lane = threadIdx.x & 63;
    const f16* A = t1b + (size_t)slab * ND128;

    h8 bfr[2][4];
#pragma unroll
    for (int nt = 0; nt < 2; ++nt)
#pragma unroll
        for (int kb = 0; kb < 4; ++kb) {
            int ntg = ch * 8 + 2 * w + nt;
            bfr[nt][kb] = *(const h8*)(W1b + (size_t)((ntg * 4 + kb) * 64 + lane) * 8);
        }

    f4 acc[4][2];
    f4 zero = {0.f, 0.f, 0.f, 0.f};
#pragma unroll
    for (int m = 0; m < 4; ++m) { acc[m][0] = zero; acc[m][1] = zero; }
#pragma unroll
    for (int m = 0; m < 4; ++m) {
        int mg = mh * 4 + m;
#pragma unroll
        for (int kb = 0; kb < 4; ++kb) {
            h8 a = *(const h8*)(A + (size_t)((kb * 8 + mg) * 64 + lane) * 8);
            acc[m][0] = __builtin_amdgcn_mfma_f32_16x16x32_f16(bfr[0][kb], a, acc[m][0], 0, 0, 0);
            acc[m][1] = __builtin_amdgcn_mfma_f32_16x16x32_f16(bfr[1][kb], a, acc[m][1], 0, 0, 0);
        }
    }

    const int rl = lane & 15, quad = lane >> 4;
    const int kbu = ch * 4 + w;
    float4 ba[2];
#pragma unroll
    for (int nt = 0; nt < 2; ++nt)
        ba[nt] = *(const float4*)(badj + ch * 128 + w * 32 + nt * 16 + quad * 4);
#pragma unroll
    for (int m = 0; m < 4; ++m) {
        int mg = mh * 4 + m;
        int gr = slab * 128 + mg * 16 + rl;
        if (gr < N) {
#pragma unroll
            for (int nt = 0; nt < 2; ++nt) {
                h4 o;
                o[0] = (f16)fmaxf(acc[m][nt][0] + ba[nt].x, 0.f);
                o[1] = (f16)fmaxf(acc[m][nt][1] + ba[nt].y, 0.f);
                o[2] = (f16)fmaxf(acc[m][nt][2] + ba[nt].z, 0.f);
                o[3] = (f16)fmaxf(acc[m][nt][3] + ba[nt].w, 0.f);
                *(h4*)(ub + (size_t)slab * 32768 +
                       (size_t)(((kbu * 8 + mg) * 64 + (nt * 2 + (quad >> 1)) * 16 + rl) * 8 +
                                (quad & 1) * 4)) = o;
            }
        }
    }
}

// --- FFN2: t2 = (s1*t1 + b1v + b2) + u @ W2^T; fp32 out; BN2 sums. ---------
// grid (slabs, 4): blockIdx.y picks pairs of m-tiles.
__global__ __launch_bounds__(256) void k_ffn2(
    const f16* __restrict__ ub, const f16* __restrict__ W2b,
    const f16* __restrict__ t1b,
    const float* __restrict__ sfold, const float* __restrict__ bfold,
    const float* __restrict__ b2, float* __restrict__ out,
    float* __restrict__ bn, int N)
{
    __shared__ float csum[128], csq[128], sS[128], sB[128];
    const int tid = threadIdx.x, slab = blockIdx.x, mh = blockIdx.y;
    const int w = tid >> 6, lane = tid & 63;
    if (tid < 128) {
        csum[tid] = 0.f; csq[tid] = 0.f;
        sS[tid] = sfold[tid]; sB[tid] = bfold[tid] + b2[tid];
    }
    __syncthreads();
    const f16* A = ub + (size_t)slab * 32768;
    const f16* T1 = t1b + (size_t)slab * ND128;

    h8 bfr[2][8];
#pragma unroll
    for (int nt = 0; nt < 2; ++nt)
#pragma unroll
        for (int kb = 0; kb < 8; ++kb)
            bfr[nt][kb] = *(const h8*)(W2b + (size_t)(((2 * w + nt) * 8 + kb) * 64 + lane) * 8);

    f4 acc[2][2];
    f4 zero = {0.f, 0.f, 0.f, 0.f};
#pragma unroll
    for (int m = 0; m < 2; ++m) { acc[m][0] = zero; acc[m][1] = zero; }
#pragma unroll
    for (int m = 0; m < 2; ++m) {
        int mg = mh * 2 + m;
#pragma unroll
        for (int kb = 0; kb < 8; ++kb) {
            h8 a = *(const h8*)(A + (size_t)((kb * 8 + mg) * 64 + lane) * 8);
            acc[m][0] = __builtin_amdgcn_mfma_f32_16x16x32_f16(bfr[0][kb], a, acc[m][0], 0, 0, 0);
            acc[m][1] = __builtin_amdgcn_mfma_f32_16x16x32_f16(bfr[1][kb], a, acc[m][1], 0, 0, 0);
        }
    }

    const int rl = lane & 15, quad = lane >> 4;
    float pcs[2][4], pcq[2][4];
#pragma unroll
    for (int nt = 0; nt < 2; ++nt)
#pragma unroll
        for (int r = 0; r < 4; ++r) { pcs[nt][r] = 0.f; pcq[nt][r] = 0.f; }

#pragma unroll
    for (int m = 0; m < 2; ++m) {
        int mg = mh * 2 + m;
        int gr = slab * 128 + mg * 16 + rl;
        if (gr < N) {
#pragma unroll
            for (int nt = 0; nt < 2; ++nt) {
                int col0 = w * 32 + nt * 16 + quad * 4;
                h4 t1v = *(const h4*)(T1 +
                    (size_t)(((w * 8 + mg) * 64 + (nt * 2 + (quad >> 1)) * 16 + rl) * 8 +
                             (quad & 1) * 4));
                float4 ss = *(const float4*)&sS[col0];
                float4 sb = *(const float4*)&sB[col0];
                float4 o;
                o.x = acc[m][nt][0] + fmaf(ss.x, (float)t1v[0], sb.x);
                o.y = acc[m][nt][1] + fmaf(ss.y, (float)t1v[1], sb.y);
                o.z = acc[m][nt][2] + fmaf(ss.z, (float)t1v[2], sb.z);
                o.w = acc[m][nt][3] + fmaf(ss.w, (float)t1v[3], sb.w);
                *(float4*)(out + (size_t)gr * 128 + col0) = o;
                pcs[nt][0] += o.x; pcq[nt][0] += o.x * o.x;
                pcs[nt][1] += o.y; pcq[nt][1] += o.y * o.y;
                pcs[nt][2] += o.z; pcq[nt][2] += o.z * o.z;
                pcs[nt][3] += o.w; pcq[nt][3] += o.w * o.w;
            }
        }
    }
#pragma unroll
    for (int nt = 0; nt < 2; ++nt)
#pragma unroll
        for (int r = 0; r < 4; ++r) {
            float s = pcs[nt][r], q = pcq[nt][r];
            s += __shfl_xor(s, 8, 16); q += __shfl_xor(q, 8, 16);
            s += __shfl_xor(s, 4, 16); q += __shfl_xor(q, 4, 16);
            s += __shfl_xor(s, 2, 16); q += __shfl_xor(q, 2, 16);
            s += __shfl_xor(s, 1, 16); q += __shfl_xor(q, 1, 16);
            if (rl == 0) {
                int cl = w * 32 + nt * 16 + quad * 4 + r;
                atomicAdd(&csum[cl], s);
                atomicAdd(&csq[cl], q);
            }
        }
    __syncthreads();
    if (tid < 128) {
        atomicAdd(bn + 256 + tid, csum[tid]);
        atomicAdd(bn + 384 + tid, csq[tid]);
    }
}

// --- BN2 normalize in place ------------------------------------------------
__global__ __launch_bounds__(256) void k_bn2(
    float* __restrict__ out, const float* __restrict__ bn,
    const float* __restrict__ g2, const float* __restrict__ bb2, int N)
{
    __shared__ float sS[128], sB[128];
    const int tid = threadIdx.x;
    if (tid < 128) {
        float invN = 1.f / (float)N;
        float mu = bn[256 + tid] * invN;
        float var = bn[384 + tid] * invN - mu * mu;
        float scl = g2[tid] * rsqrtf(var + 1e-5f);
        sS[tid] = scl;
        sB[tid] = bb2[tid] - mu * scl;
    }
    __syncthreads();
    size_t idx = (size_t)blockIdx.x * 256 + tid;
    size_t total = (size_t)N * 32;
    if (idx < total) {
        int c0 = (int)((idx * 4) & 127);
        float4 v = *(const float4*)(out + idx * 4);
        v.x = fmaf(v.x, sS[c0 + 0], sB[c0 + 0]);
        v.y = fmaf(v.y, sS[c0 + 1], sB[c0 + 1]);
        v.z = fmaf(v.z, sS[c0 + 2], sB[c0 + 2]);
        v.w = fmaf(v.w, sS[c0 + 3], sB[c0 + 3]);
        *(float4*)(out + idx * 4) = v;
    }
}

extern "C" void kernel_launch(void* const* d_in, const int* in_sizes, int n_in,
                              void* d_out, int out_size, void* d_ws, size_t ws_size,
                              hipStream_t stream)
{
    const float* h   = (const float*)d_in[0];
    const int*   src = (const int*)d_in[1];
    const int*   dst = (const int*)d_in[2];
    const float* WQ  = (const float*)d_in[3];
    const float* WK  = (const float*)d_in[4];
    const float* WV  = (const float*)d_in[5];
    const float* WO  = (const float*)d_in[6];
    const float* bO  = (const float*)d_in[7];
    const float* W1  = (const float*)d_in[8];
    const float* b1  = (const float*)d_in[9];
    const float* W2  = (const float*)d_in[10];
    const float* b2  = (const float*)d_in[11];
    const float* g1  = (const float*)d_in[12];
    const float* bb1 = (const float*)d_in[13];
    const float* g2  = (const float*)d_in[14];
    const float* bb2 = (const float*)d_in[15];
    float* out = (float*)d_out;

    int N = in_sizes[0] / 128;
    int E = in_sizes[1];
    int slabs = (N + 127) / 128;
    int nsb = (N + 2047) / 2048;               // scan blocks (~25)
    int nhb = (E + 255) / 256;                 // edge blocks (~2500)
    const size_t B1 = (size_t)slabs * 32768;   // bytes of one f16 N_pad x 128 buffer

    char* Wp = (char*)d_ws;
    f16* hb  = (f16*)Wp;                       // h f16 frags, lives through oproj
    f16* Qb  = (f16*)(Wp + B1);                // B1
    unsigned char* KV8 = (unsigned char*)(Wp + 2 * B1);  // B1 (fp8 K|V 256B rows)
    f16* attnf = (f16*)(Wp + 3 * B1);          // B1
    f16* t1b = (f16*)(Wp + 4 * B1);            // B1
    f16* ub  = (f16*)(Wp + B1);                // 2*B1, overlays Qb+KV8 after attn
    const size_t base = 5 * B1;
    f16* Wqb = (f16*)(Wp + base);
    f16* Wkb = (f16*)(Wp + base + 32768);
    f16* Wvb = (f16*)(Wp + base + 65536);
    f16* Wob = (f16*)(Wp + base + 98304);
    f16* W1b = (f16*)(Wp + base + 131072);
    f16* W2b = (f16*)(Wp + base + 196608);
    float* badj  = (float*)(Wp + base + 262144);
    float* sfold = (float*)(Wp + base + 263168);
    float* bfold = (float*)(Wp + base + 263680);
    float* bn    = (float*)(Wp + base + 264192);     // 512 floats (memset)
    int* bsum    = (int*)(Wp + base + 266240);       // 64 ints (memset)
    int* cursor  = (int*)(Wp + base + 266496);       // N ints (memset)
    int* rowptr  = (int*)(Wp + base + 266496 + (size_t)N * 4);
    int* csr     = (int*)(Wp + base + 266496 + (size_t)N * 8 + 8);

    // zero bn(2048) + bsum(256) + cursor(N*4) in one memset
    hipMemsetAsync(Wp + base + 264192, 0, 2304 + (size_t)N * 4, stream);
    k_prep_hist<<<nhb + slabs * 2, 256, 0, stream>>>(
        h, hb, WQ, WK, WV, WO, W2, Wqb, Wkb, Wvb, Wob, W2b, cursor, dst, N, E, nhb);
    k_qkv<<<dim3(slabs, 3, 2), 256, 0, stream>>>(hb, Wqb, Wkb, Wvb, Qb, KV8, N);
    k_scanA<<<nsb, 256, 0, stream>>>(cursor, bsum, N);
    k_scanC<<<nsb, 256, 0, stream>>>(cursor, bsum, rowptr, cursor, N, nsb);
    k_scatter<<<nhb, 256, 0, stream>>>(src, dst, cursor, csr, E);
    k_attn<<<(N + 3) / 4, 256, 0, stream>>>(Qb, KV8, rowptr, csr, attnf, N);
    k_oproj<<<dim3(slabs, 4), 256, 0, stream>>>(attnf, Wob, hb, bO, t1b, bn, N);
    k_fold1<<<256, 128, 0, stream>>>(bn, g1, bb1, W1, b1, W1b, badj, sfold, bfold, N);
    k_ffn1<<<dim3(slabs, 2, 2), 256, 0, stream>>>(t1b, W1b, badj, ub, N);
    k_ffn2<<<dim3(slabs, 4), 256, 0, stream>>>(ub, W2b, t1b, sfold, bfold, b2, out, bn, N);
    k_bn2<<<(int)(((size_t)N * 32 + 255) / 256), 256, 0, stream>>>(out, bn, g2, bb2, N);
}

// Round 7
// 308.424 us; speedup vs baseline: 2.1601x; 1.1077x over previous
//
#include <hip/hip_runtime.h>
#include <math.h>

// ---------------------------------------------------------------------------
// GraphTransformerLayer N=50000, E=640000, D=128, H=8, DH=16  (gfx950)
// Round 18: best-of recombination. Cross-round evidence: FAT blocks win
// (R11 318.6 < all split variants). Revert GEMMs to 8-m-tile fat shapes,
// keep fp8-KV attn + f16 residual + fused prep|hist front. New: ffn2 emits
// f16 t2 frags (BN2 stats from rounded values), bn2 reads frags -> fp32 out.
//
// Fragment order for an MxK slab (M=128, K=KB*32):
//   elem index = ((kb*8 + mtile)*64 + lane)*8 + j
//   row = mtile*16 + (lane&15),  col = kb*32 + (lane>>4)*8 + j
// Swapped-operand MFMA: mfma(Wfrag, hfrag) -> C^T: row = m*16+(lane&15),
// cols = w*32+nt*16+quad*4+{0..3} contiguous.
// ---------------------------------------------------------------------------

#define ND128 16384
typedef _Float16 f16;
typedef __attribute__((ext_vector_type(8))) _Float16 h8;
typedef __attribute__((ext_vector_type(4))) _Float16 h4;
typedef __attribute__((ext_vector_type(2))) _Float16 h2;
typedef __attribute__((ext_vector_type(4))) float f4;
typedef __attribute__((ext_vector_type(2))) float ff2;

__device__ __forceinline__ float fast_exp2(float x) {
#if __has_builtin(__builtin_amdgcn_exp2f)
    return __builtin_amdgcn_exp2f(x);
#else
    return exp2f(x);
#endif
}

template <int CTRL>
__device__ __forceinline__ float dppadd(float x) {
    int t = __builtin_amdgcn_update_dpp(0, __float_as_int(x), CTRL, 0xF, 0xF, false);
    return x + __int_as_float(t);
}
__device__ __forceinline__ float wsum8(float p) {
    p = dppadd<0xB1>(p);    // quad_perm [1,0,3,2]
    p = dppadd<0x4E>(p);    // quad_perm [2,3,0,1]
    p = dppadd<0x141>(p);   // row_half_mirror
    return p;
}

__device__ __forceinline__ ff2 fp8x2_dec(unsigned v) {
#if __has_builtin(__builtin_amdgcn_cvt_pk_f32_fp8)
    return __builtin_amdgcn_cvt_pk_f32_fp8((int)v, false);
#else
    ff2 r;
    unsigned b0 = v & 0xffu, b1 = (v >> 8) & 0xffu;
    {
        unsigned e = (b0 >> 3) & 15u, m = b0 & 7u;
        float x = e ? __uint_as_float(((e + 120u) << 23) | (m << 20)) : (float)m * 0.001953125f;
        r.x = (b0 & 0x80u) ? -x : x;
    }
    {
        unsigned e = (b1 >> 3) & 15u, m = b1 & 7u;
        float x = e ? __uint_as_float(((e + 120u) << 23) | (m << 20)) : (float)m * 0.001953125f;
        r.y = (b1 & 0x80u) ? -x : x;
    }
    return r;
#endif
}

#if !__has_builtin(__builtin_amdgcn_cvt_pk_fp8_f32)
__device__ __forceinline__ unsigned char fp8_1(float f) {
    float a = fabsf(f);
    unsigned sg = (__float_as_uint(f) >> 31) << 7;
    if (a >= 448.f) return (unsigned char)(sg | 0x7E);
    if (a < 0.0009765625f) return (unsigned char)sg;
    int E; float m = frexpf(a, &E);
    if (E - 1 < -6) {
        int q = (int)rintf(a * 512.f);
        if (q > 7) return (unsigned char)(sg | 0x08);
        return (unsigned char)(sg | q);
    }
    int q = (int)rintf(m * 16.f);
    if (q == 16) { q = 8; E += 1; }
    int Ef = E - 1 + 7;
    if (Ef > 15) return (unsigned char)(sg | 0x7E);
    return (unsigned char)(sg | (Ef << 3) | (q - 8));
}
#endif

__device__ __forceinline__ unsigned fp8_pack4(float a0, float a1, float a2, float a3) {
#if __has_builtin(__builtin_amdgcn_cvt_pk_fp8_f32)
    int pk = __builtin_amdgcn_cvt_pk_fp8_f32(a0, a1, 0, false);
    pk = __builtin_amdgcn_cvt_pk_fp8_f32(a2, a3, pk, true);
    return (unsigned)pk;
#else
    return (unsigned)fp8_1(a0) | ((unsigned)fp8_1(a1) << 8) |
           ((unsigned)fp8_1(a2) << 16) | ((unsigned)fp8_1(a3) << 24);
#endif
}

// --- K1: hist (blocks [0,nhb)) UNION prep (blocks [nhb, nhb+slabs*2)). ----
__global__ __launch_bounds__(256) void k_prep_hist(
    const float* __restrict__ h, f16* __restrict__ hb,
    const float* __restrict__ WQ, const float* __restrict__ WK,
    const float* __restrict__ WV, const float* __restrict__ WO,
    const float* __restrict__ W2,
    f16* __restrict__ Wqb, f16* __restrict__ Wkb,
    f16* __restrict__ Wvb, f16* __restrict__ Wob, f16* __restrict__ W2b,
    int* __restrict__ cursor, const int* __restrict__ dst,
    int N, int E, int nhb)
{
    const int tid = threadIdx.x;
    if (blockIdx.x < (unsigned)nhb) {
        int e = blockIdx.x * 256 + tid;
        if (e < E) atomicAdd(&cursor[dst[e]], 1);
        return;
    }
    const int p = blockIdx.x - nhb;
    const int slab = p >> 1, my = p & 1;
#pragma unroll
    for (int it2 = 0; it2 < 4; ++it2) {
        int it = my * 4 + it2;
        int cid = it * 256 + tid;              // 0..2047
        int lane = cid & 63;
        int m = (cid >> 6) & 7;
        int kb = cid >> 9;
        int row = slab * 128 + m * 16 + (lane & 15);
        int col = kb * 32 + (lane >> 4) * 8;
        f16 o8[8];
        if (row < N) {
            const float* pp = h + (size_t)row * 128 + col;
            float4 f0 = *(const float4*)pp;
            float4 f1 = *(const float4*)(pp + 4);
            o8[0] = (f16)f0.x; o8[1] = (f16)f0.y; o8[2] = (f16)f0.z; o8[3] = (f16)f0.w;
            o8[4] = (f16)f1.x; o8[5] = (f16)f1.y; o8[6] = (f16)f1.z; o8[7] = (f16)f1.w;
        } else {
#pragma unroll
            for (int j = 0; j < 8; ++j) o8[j] = (f16)0.f;
        }
        *(h8*)(hb + (size_t)slab * ND128 + (size_t)cid * 8) = *(const h8*)o8;
    }
    if (slab < 6 && my == 1) {
        const float* Wsrc; f16* dstw; int K, base;
        if (slab < 4) {
            Wsrc = slab == 0 ? WQ : slab == 1 ? WK : slab == 2 ? WV : WO;
            dstw = slab == 0 ? Wqb : slab == 1 ? Wkb : slab == 2 ? Wvb : Wob;
            K = 128; base = 0;
        } else {
            Wsrc = W2; dstw = W2b; K = 256; base = (slab - 4) * 2048;
        }
#pragma unroll
        for (int it = 0; it < 8; ++it) {
            int cid = base + it * 256 + tid;
            int lane = cid & 63;
            int kb, nt;
            if (K == 128) { kb = (cid >> 6) & 3; nt = cid >> 8; }
            else          { kb = (cid >> 6) & 7; nt = cid >> 9; }
            int row = nt * 16 + (lane & 15);
            int col = kb * 32 + (lane >> 4) * 8;
            const float* pp = Wsrc + (size_t)row * K + col;
            f16 o8[8];
#pragma unroll
            for (int j = 0; j < 8; ++j) o8[j] = (f16)pp[j];
            *(h8*)(dstw + (size_t)cid * 8) = *(const h8*)o8;
        }
    }
}

// --- K2: QKV fat grid (slabs, 3). Q f16 rows; K/V fp8 in 256B rows of KV8. -
__global__ __launch_bounds__(256) void k_qkv(
    const f16* __restrict__ hb, const f16* __restrict__ Wqb,
    const f16* __restrict__ Wkb, const f16* __restrict__ Wvb,
    f16* __restrict__ Qb, unsigned char* __restrict__ KV8, int N)
{
    const int slab = blockIdx.x, oidx = blockIdx.y;
    const int w = threadIdx.x >> 6, lane = threadIdx.x & 63;
    const f16* __restrict__ Wb = oidx == 0 ? Wqb : oidx == 1 ? Wkb : Wvb;
    const f16* A = hb + (size_t)slab * ND128;

    h8 bfr[2][4];
#pragma unroll
    for (int nt = 0; nt < 2; ++nt)
#pragma unroll
        for (int kb = 0; kb < 4; ++kb)
            bfr[nt][kb] = *(const h8*)(Wb + (size_t)(((2 * w + nt) * 4 + kb) * 64 + lane) * 8);

    f4 acc[8][2];
    f4 zero = {0.f, 0.f, 0.f, 0.f};
#pragma unroll
    for (int m = 0; m < 8; ++m) { acc[m][0] = zero; acc[m][1] = zero; }

#pragma unroll
    for (int m = 0; m < 8; ++m) {
#pragma unroll
        for (int kb = 0; kb < 4; ++kb) {
            h8 a = *(const h8*)(A + (size_t)((kb * 8 + m) * 64 + lane) * 8);
            acc[m][0] = __builtin_amdgcn_mfma_f32_16x16x32_f16(bfr[0][kb], a, acc[m][0], 0, 0, 0);
            acc[m][1] = __builtin_amdgcn_mfma_f32_16x16x32_f16(bfr[1][kb], a, acc[m][1], 0, 0, 0);
        }
    }

    const int rl = lane & 15, quad = lane >> 4;
    if (oidx == 0) {
#pragma unroll
        for (int m = 0; m < 8; ++m) {
            int gr = slab * 128 + m * 16 + rl;
            if (gr < N) {
#pragma unroll
                for (int nt = 0; nt < 2; ++nt) {
                    h4 o;
                    o[0] = (f16)acc[m][nt][0]; o[1] = (f16)acc[m][nt][1];
                    o[2] = (f16)acc[m][nt][2]; o[3] = (f16)acc[m][nt][3];
                    *(h4*)(Qb + (size_t)gr * 128 + w * 32 + nt * 16 + quad * 4) = o;
                }
            }
        }
    } else {
        const int voff = (oidx == 2) ? 128 : 0;
#pragma unroll
        for (int m = 0; m < 8; ++m) {
            int gr = slab * 128 + m * 16 + rl;
            if (gr < N) {
#pragma unroll
                for (int nt = 0; nt < 2; ++nt) {
                    unsigned pk = fp8_pack4(acc[m][nt][0], acc[m][nt][1],
                                            acc[m][nt][2], acc[m][nt][3]);
                    *(unsigned*)(KV8 + (size_t)gr * 256 + voff + w * 32 + nt * 16 + quad * 4) = pk;
                }
            }
        }
    }
}

// --- scan part A ----------------------------------------------------------
__global__ __launch_bounds__(256) void k_scanA(
    const int* __restrict__ cnt, int* __restrict__ bsum, int N)
{
    const int t = threadIdx.x;
    int base = blockIdx.x * 2048 + t * 8;
    int s = 0;
#pragma unroll
    for (int j = 0; j < 8; ++j) {
        int idx = base + j;
        if (idx < N) s += cnt[idx];
    }
#pragma unroll
    for (int off = 32; off; off >>= 1) s += __shfl_down(s, off, 64);
    __shared__ int ws4[4];
    if ((t & 63) == 0) ws4[t >> 6] = s;
    __syncthreads();
    if (t == 0) bsum[blockIdx.x] = ws4[0] + ws4[1] + ws4[2] + ws4[3];
}

// --- scan part C ----------------------------------------------------------
__global__ __launch_bounds__(256) void k_scanC(
    const int* __restrict__ cnt, const int* __restrict__ bsum,
    int* __restrict__ rowptr, int* __restrict__ cursor, int N, int nsb)
{
    const int t = threadIdx.x, b = blockIdx.x;
    __shared__ int sboff;
    if (t == 0) {
        int r = 0;
        for (int i2 = 0; i2 < b; ++i2) r += bsum[i2];
        sboff = r;
    }
    if (t == 64 && b == nsb - 1) {
        int r = 0;
        for (int i2 = 0; i2 < nsb; ++i2) r += bsum[i2];
        rowptr[N] = r;
    }
    int base = b * 2048 + t * 8;
    int loc[8];
    int s = 0;
#pragma unroll
    for (int j = 0; j < 8; ++j) {
        int idx = base + j;
        loc[j] = (idx < N) ? cnt[idx] : 0;
        s += loc[j];
    }
    __shared__ int part[256];
    part[t] = s;
    __syncthreads();
    for (int off = 1; off < 256; off <<= 1) {
        int v = (t >= off) ? part[t - off] : 0;
        __syncthreads();
        part[t] += v;
        __syncthreads();
    }
    int run = sboff + (t ? part[t - 1] : 0);
#pragma unroll
    for (int j = 0; j < 8; ++j) {
        int idx = base + j;
        if (idx < N) { rowptr[idx] = run; cursor[idx] = run; run += loc[j]; }
    }
}

// --- scatter edges into CSR ------------------------------------------------
__global__ __launch_bounds__(256) void k_scatter(
    const int* __restrict__ src, const int* __restrict__ dst,
    int* __restrict__ cursor, int* __restrict__ csr_src, int E)
{
    int e = blockIdx.x * 256 + threadIdx.x;
    if (e < E) {
        int pos = atomicAdd(&cursor[dst[e]], 1);
        csr_src[pos] = src[e];
    }
}

// --- attention: one wave per node, lane owns channels (2l, 2l+1). ----------
__global__ __launch_bounds__(256) void k_attn(
    const f16* __restrict__ Qb, const unsigned char* __restrict__ KV8,
    const int* __restrict__ rowptr, const int* __restrict__ csr_src,
    f16* __restrict__ attnf, int N)
{
    const int node = blockIdx.x * 4 + (threadIdx.x >> 6);
    const int lane = threadIdx.x & 63;
    if (node >= N) return;
    const int beg = rowptr[node], end = rowptr[node + 1];

    float qx, qy;
    {
        h2 q2 = ((const h2*)(Qb + (size_t)node * 128))[lane];
        const float SCL = 0.25f * 1.44269504f;
        qx = (float)q2[0] * SCL;
        qy = (float)q2[1] * SCL;
    }
    const float CLP = 5.f * 1.44269504f;

    float axA = 0.f, ayA = 0.f, axB = 0.f, ayB = 0.f, zA = 0.f, zB = 0.f;
    int i = beg;
    for (; i + 3 < end; i += 4) {
        int s0 = csr_src[i], s1 = csr_src[i + 1];
        int s2 = csr_src[i + 2], s3 = csr_src[i + 3];
        unsigned k0 = *(const unsigned short*)(KV8 + (size_t)s0 * 256 + 2 * lane);
        unsigned k1 = *(const unsigned short*)(KV8 + (size_t)s1 * 256 + 2 * lane);
        unsigned k2 = *(const unsigned short*)(KV8 + (size_t)s2 * 256 + 2 * lane);
        unsigned k3 = *(const unsigned short*)(KV8 + (size_t)s3 * 256 + 2 * lane);
        unsigned v0 = *(const unsigned short*)(KV8 + (size_t)s0 * 256 + 128 + 2 * lane);
        unsigned v1 = *(const unsigned short*)(KV8 + (size_t)s1 * 256 + 128 + 2 * lane);
        unsigned v2 = *(const unsigned short*)(KV8 + (size_t)s2 * 256 + 128 + 2 * lane);
        unsigned v3 = *(const unsigned short*)(KV8 + (size_t)s3 * 256 + 128 + 2 * lane);
        ff2 kf0 = fp8x2_dec(k0), kf1 = fp8x2_dec(k1);
        ff2 kf2 = fp8x2_dec(k2), kf3 = fp8x2_dec(k3);
        float p0 = fmaf(qx, kf0.x, qy * kf0.y);
        float p1 = fmaf(qx, kf1.x, qy * kf1.y);
        float p2 = fmaf(qx, kf2.x, qy * kf2.y);
        float p3 = fmaf(qx, kf3.x, qy * kf3.y);
        p0 = wsum8(p0); p1 = wsum8(p1); p2 = wsum8(p2); p3 = wsum8(p3);
        float sc0 = fast_exp2(fminf(fmaxf(p0, -CLP), CLP));
        float sc1 = fast_exp2(fminf(fmaxf(p1, -CLP), CLP));
        float sc2 = fast_exp2(fminf(fmaxf(p2, -CLP), CLP));
        float sc3 = fast_exp2(fminf(fmaxf(p3, -CLP), CLP));
        ff2 vf0 = fp8x2_dec(v0), vf1 = fp8x2_dec(v1);
        ff2 vf2 = fp8x2_dec(v2), vf3 = fp8x2_dec(v3);
        axA = fmaf(vf0.x, sc0, axA); ayA = fmaf(vf0.y, sc0, ayA);
        axB = fmaf(vf1.x, sc1, axB); ayB = fmaf(vf1.y, sc1, ayB);
        axA = fmaf(vf2.x, sc2, axA); ayA = fmaf(vf2.y, sc2, ayA);
        axB = fmaf(vf3.x, sc3, axB); ayB = fmaf(vf3.y, sc3, ayB);
        zA += sc0 + sc2; zB += sc1 + sc3;
    }
    for (; i < end; ++i) {
        int s0 = csr_src[i];
        unsigned k0 = *(const unsigned short*)(KV8 + (size_t)s0 * 256 + 2 * lane);
        unsigned v0 = *(const unsigned short*)(KV8 + (size_t)s0 * 256 + 128 + 2 * lane);
        ff2 kf0 = fp8x2_dec(k0);
        float p0 = fmaf(qx, kf0.x, qy * kf0.y);
        p0 = wsum8(p0);
        float sc0 = fast_exp2(fminf(fmaxf(p0, -CLP), CLP));
        ff2 vf0 = fp8x2_dec(v0);
        axA = fmaf(vf0.x, sc0, axA); ayA = fmaf(vf0.y, sc0, ayA);
        zA += sc0;
    }
    float inv = 1.f / (zA + zB);
    h2 o2;
    o2[0] = (f16)((axA + axB) * inv);
    o2[1] = (f16)((ayA + ayB) * inv);
    int slab = node >> 7, m = (node >> 4) & 7, lr = node & 15;
    int kb = lane >> 4, quad2 = (lane & 15) >> 2, j = (lane & 3) * 2;
    *(h2*)(attnf + (size_t)slab * ND128 +
           (size_t)(((kb * 8 + m) * 64 + lr + 16 * quad2) * 8 + j)) = o2;
}

// --- O-proj (FAT): t1 = attn @ WO^T + h + bO -> f16 frag t1b; BN1 sums. ----
// grid = slabs. Residual from hb f16 frags (same addressing as t1b write).
__global__ __launch_bounds__(256) void k_oproj(
    const f16* __restrict__ attnf, const f16* __restrict__ Wob,
    const f16* __restrict__ hbf, const float* __restrict__ bO,
    f16* __restrict__ t1b, float* __restrict__ bn, int N)
{
    __shared__ float csum[128], csq[128];
    const int tid = threadIdx.x, slab = blockIdx.x;
    const int w = tid >> 6, lane = tid & 63;
    if (tid < 128) { csum[tid] = 0.f; csq[tid] = 0.f; }
    __syncthreads();
    const f16* A = attnf + (size_t)slab * ND128;
    const f16* HB = hbf + (size_t)slab * ND128;

    h8 bfr[2][4];
#pragma unroll
    for (int nt = 0; nt < 2; ++nt)
#pragma unroll
        for (int kb = 0; kb < 4; ++kb)
            bfr[nt][kb] = *(const h8*)(Wob + (size_t)(((2 * w + nt) * 4 + kb) * 64 + lane) * 8);

    f4 acc[8][2];
    f4 zero = {0.f, 0.f, 0.f, 0.f};
#pragma unroll
    for (int m = 0; m < 8; ++m) { acc[m][0] = zero; acc[m][1] = zero; }
#pragma unroll
    for (int m = 0; m < 8; ++m) {
#pragma unroll
        for (int kb = 0; kb < 4; ++kb) {
            h8 a = *(const h8*)(A + (size_t)((kb * 8 + m) * 64 + lane) * 8);
            acc[m][0] = __builtin_amdgcn_mfma_f32_16x16x32_f16(bfr[0][kb], a, acc[m][0], 0, 0, 0);
            acc[m][1] = __builtin_amdgcn_mfma_f32_16x16x32_f16(bfr[1][kb], a, acc[m][1], 0, 0, 0);
        }
    }

    const int rl = lane & 15, quad = lane >> 4;
    float4 bo[2];
#pragma unroll
    for (int nt = 0; nt < 2; ++nt)
        bo[nt] = *(const float4*)(bO + w * 32 + nt * 16 + quad * 4);
    float pcs[2][4], pcq[2][4];
#pragma unroll
    for (int nt = 0; nt < 2; ++nt)
#pragma unroll
        for (int r = 0; r < 4; ++r) { pcs[nt][r] = 0.f; pcq[nt][r] = 0.f; }

#pragma unroll
    for (int m = 0; m < 8; ++m) {
        int gr = slab * 128 + m * 16 + rl;
        if (gr < N) {
#pragma unroll
            for (int nt = 0; nt < 2; ++nt) {
                size_t fidx = (size_t)(((w * 8 + m) * 64 + (nt * 2 + (quad >> 1)) * 16 + rl) * 8 +
                                       (quad & 1) * 4);
                h4 hv4 = *(const h4*)(HB + fidx);
                float v0 = acc[m][nt][0] + (float)hv4[0] + bo[nt].x;
                float v1 = acc[m][nt][1] + (float)hv4[1] + bo[nt].y;
                float v2 = acc[m][nt][2] + (float)hv4[2] + bo[nt].z;
                float v3 = acc[m][nt][3] + (float)hv4[3] + bo[nt].w;
                h4 o; o[0] = (f16)v0; o[1] = (f16)v1; o[2] = (f16)v2; o[3] = (f16)v3;
                *(h4*)(t1b + (size_t)slab * ND128 + fidx) = o;
                pcs[nt][0] += v0; pcq[nt][0] += v0 * v0;
                pcs[nt][1] += v1; pcq[nt][1] += v1 * v1;
                pcs[nt][2] += v2; pcq[nt][2] += v2 * v2;
                pcs[nt][3] += v3; pcq[nt][3] += v3 * v3;
            }
        }
    }
#pragma unroll
    for (int nt = 0; nt < 2; ++nt)
#pragma unroll
        for (int r = 0; r < 4; ++r) {
            float s = pcs[nt][r], q = pcq[nt][r];
            s += __shfl_xor(s, 8, 16); q += __shfl_xor(q, 8, 16);
            s += __shfl_xor(s, 4, 16); q += __shfl_xor(q, 4, 16);
            s += __shfl_xor(s, 2, 16); q += __shfl_xor(q, 2, 16);
            s += __shfl_xor(s, 1, 16); q += __shfl_xor(q, 1, 16);
            if (rl == 0) {
                int cl = w * 32 + nt * 16 + quad * 4 + r;
                atomicAdd(&csum[cl], s);
                atomicAdd(&csq[cl], q);
            }
        }
    __syncthreads();
    if (tid < 128) {
        atomicAdd(bn + tid, csum[tid]);
        atomicAdd(bn + 128 + tid, csq[tid]);
    }
}

// --- fold BN1 into W1/bias. 256 blocks (one per W1 row). -------------------
__global__ __launch_bounds__(128) void k_fold1(
    const float* __restrict__ bn, const float* __restrict__ g1,
    const float* __restrict__ bb1, const float* __restrict__ W1,
    const float* __restrict__ b1, f16* __restrict__ W1b,
    float* __restrict__ badj, float* __restrict__ sfold,
    float* __restrict__ bfold, int N)
{
    const int o = blockIdx.x, i = threadIdx.x;
    float invN = 1.f / (float)N;
    float mu = bn[i] * invN;
    float var = bn[128 + i] * invN - mu * mu;
    float s = g1[i] * rsqrtf(var + 1e-5f);
    float bb = bb1[i] - mu * s;
    if (o == 0) { sfold[i] = s; bfold[i] = bb; }
    float wv = W1[(size_t)o * 128 + i];
    __shared__ float red[128];
    red[i] = wv * bb;
    const int nt = o >> 4, lanelow = o & 15;
    const int kb = i >> 5, quad = (i >> 3) & 3, j = i & 7;
    W1b[(size_t)(((nt * 4 + kb) * 64 + lanelow + 16 * quad) * 8 + j)] = (f16)(wv * s);
    __syncthreads();
#pragma unroll
    for (int off = 64; off; off >>= 1) {
        if (i < off) red[i] += red[i + off];
        __syncthreads();
    }
    if (i == 0) badj[o] = b1[o] + red[0];
}

// --- FFN1 (FAT): u = relu(t1b @ W1s^T + badj). grid (slabs, 2). ------------
__global__ __launch_bounds__(256) void k_ffn1(
    const f16* __restrict__ t1b, const f16* __restrict__ W1b,
    const float* __restrict__ badj, f16* __restrict__ ub, int N)
{
    const int slab = blockIdx.x, ch = blockIdx.y;
    const int w = threadIdx.x >> 6, lane = threadIdx.x & 63;
    const f16* A = t1b + (size_t)slab * ND128;

    h8 bfr[2][4];
#pragma unroll
    for (int nt = 0; nt < 2; ++nt)
#pragma unroll
        for (int kb = 0; kb < 4; ++kb) {
            int ntg = ch * 8 + 2 * w + nt;
            bfr[nt][kb] = *(const h8*)(W1b + (size_t)((ntg * 4 + kb) * 64 + lane) * 8);
        }

    f4 acc[8][2];
    f4 zero = {0.f, 0.f, 0.f, 0.f};
#pragma unroll
    for (int m = 0; m < 8; ++m) { acc[m][0] = zero; acc[m][1] = zero; }
#pragma unroll
    for (int m = 0; m < 8; ++m) {
#pragma unroll
        for (int kb = 0; kb < 4; ++kb) {
            h8 a = *(const h8*)(A + (size_t)((kb * 8 + m) * 64 + lane) * 8);
            acc[m][0] = __builtin_amdgcn_mfma_f32_16x16x32_f16(bfr[0][kb], a, acc[m][0], 0, 0, 0);
            acc[m][1] = __builtin_amdgcn_mfma_f32_16x16x32_f16(bfr[1][kb], a, acc[m][1], 0, 0, 0);
        }
    }

    const int rl = lane & 15, quad = lane >> 4;
    const int kbu = ch * 4 + w;
    float4 ba[2];
#pragma unroll
    for (int nt = 0; nt < 2; ++nt)
        ba[nt] = *(const float4*)(badj + ch * 128 + w * 32 + nt * 16 + quad * 4);
#pragma unroll
    for (int m = 0; m < 8; ++m) {
        int gr = slab * 128 + m * 16 + rl;
        if (gr < N) {
#pragma unroll
            for (int nt = 0; nt < 2; ++nt) {
                h4 o;
                o[0] = (f16)fmaxf(acc[m][nt][0] + ba[nt].x, 0.f);
                o[1] = (f16)fmaxf(acc[m][nt][1] + ba[nt].y, 0.f);
                o[2] = (f16)fmaxf(acc[m][nt][2] + ba[nt].z, 0.f);
                o[3] = (f16)fmaxf(acc[m][nt][3] + ba[nt].w, 0.f);
                *(h4*)(ub + (size_t)slab * 32768 +
                       (size_t)(((kbu * 8 + m) * 64 + (nt * 2 + (quad >> 1)) * 16 + rl) * 8 +
                                (quad & 1) * 4)) = o;
            }
        }
    }
}

// --- FFN2 (FAT): t2 = (s1*t1 + b1v + b2) + u @ W2^T -> f16 frag t2f; -------
// BN2 stats computed FROM THE ROUNDED f16 values (stats/normalize consistent).
__global__ __launch_bounds__(256) void k_ffn2(
    const f16* __restrict__ ub, const f16* __restrict__ W2b,
    const f16* __restrict__ t1b,
    const float* __restrict__ sfold, const float* __restrict__ bfold,
    const float* __restrict__ b2, f16* __restrict__ t2f,
    float* __restrict__ bn, int N)
{
    __shared__ float csum[128], csq[128], sS[128], sB[128];
    const int tid = threadIdx.x, slab = blockIdx.x;
    const int w = tid >> 6, lane = tid & 63;
    if (tid < 128) {
        csum[tid] = 0.f; csq[tid] = 0.f;
        sS[tid] = sfold[tid]; sB[tid] = bfold[tid] + b2[tid];
    }
    __syncthreads();
    const f16* A = ub + (size_t)slab * 32768;
    const f16* T1 = t1b + (size_t)slab * ND128;

    h8 bfr[2][8];
#pragma unroll
    for (int nt = 0; nt < 2; ++nt)
#pragma unroll
        for (int kb = 0; kb < 8; ++kb)
            bfr[nt][kb] = *(const h8*)(W2b + (size_t)(((2 * w + nt) * 8 + kb) * 64 + lane) * 8);

    f4 acc[8][2];
    f4 zero = {0.f, 0.f, 0.f, 0.f};
#pragma unroll
    for (int m = 0; m < 8; ++m) { acc[m][0] = zero; acc[m][1] = zero; }
#pragma unroll
    for (int m = 0; m < 8; ++m) {
#pragma unroll
        for (int kb = 0; kb < 8; ++kb) {
            h8 a = *(const h8*)(A + (size_t)((kb * 8 + m) * 64 + lane) * 8);
            acc[m][0] = __builtin_amdgcn_mfma_f32_16x16x32_f16(bfr[0][kb], a, acc[m][0], 0, 0, 0);
            acc[m][1] = __builtin_amdgcn_mfma_f32_16x16x32_f16(bfr[1][kb], a, acc[m][1], 0, 0, 0);
        }
    }

    const int rl = lane & 15, quad = lane >> 4;
    float pcs[2][4], pcq[2][4];
#pragma unroll
    for (int nt = 0; nt < 2; ++nt)
#pragma unroll
        for (int r = 0; r < 4; ++r) { pcs[nt][r] = 0.f; pcq[nt][r] = 0.f; }

#pragma unroll
    for (int m = 0; m < 8; ++m) {
        int gr = slab * 128 + m * 16 + rl;
        if (gr < N) {
#pragma unroll
            for (int nt = 0; nt < 2; ++nt) {
                int col0 = w * 32 + nt * 16 + quad * 4;
                size_t fidx = (size_t)(((w * 8 + m) * 64 + (nt * 2 + (quad >> 1)) * 16 + rl) * 8 +
                                       (quad & 1) * 4);
                h4 t1v = *(const h4*)(T1 + fidx);
                float4 ss = *(const float4*)&sS[col0];
                float4 sb = *(const float4*)&sB[col0];
                h4 o2;
                o2[0] = (f16)(acc[m][nt][0] + fmaf(ss.x, (float)t1v[0], sb.x));
                o2[1] = (f16)(acc[m][nt][1] + fmaf(ss.y, (float)t1v[1], sb.y));
                o2[2] = (f16)(acc[m][nt][2] + fmaf(ss.z, (float)t1v[2], sb.z));
                o2[3] = (f16)(acc[m][nt][3] + fmaf(ss.w, (float)t1v[3], sb.w));
                *(h4*)(t2f + (size_t)slab * ND128 + fidx) = o2;
                float r0 = (float)o2[0], r1 = (float)o2[1];
                float r2 = (float)o2[2], r3 = (float)o2[3];
                pcs[nt][0] += r0; pcq[nt][0] += r0 * r0;
                pcs[nt][1] += r1; pcq[nt][1] += r1 * r1;
                pcs[nt][2] += r2; pcq[nt][2] += r2 * r2;
                pcs[nt][3] += r3; pcq[nt][3] += r3 * r3;
            }
        }
    }
#pragma unroll
    for (int nt = 0; nt < 2; ++nt)
#pragma unroll
        for (int r = 0; r < 4; ++r) {
            float s = pcs[nt][r], q = pcq[nt][r];
            s += __shfl_xor(s, 8, 16); q += __shfl_xor(q, 8, 16);
            s += __shfl_xor(s, 4, 16); q += __shfl_xor(q, 4, 16);
            s += __shfl_xor(s, 2, 16); q += __shfl_xor(q, 2, 16);
            s += __shfl_xor(s, 1, 16); q += __shfl_xor(q, 1, 16);
            if (rl == 0) {
                int cl = w * 32 + nt * 16 + quad * 4 + r;
                atomicAdd(&csum[cl], s);
                atomicAdd(&csq[cl], q);
            }
        }
    __syncthreads();
    if (tid < 128) {
        atomicAdd(bn + 256 + tid, csum[tid]);
        atomicAdd(bn + 384 + tid, csq[tid]);
    }
}

// --- BN2: read f16 t2 frags, normalize, write fp32 rows (coalesced). -------
__global__ __launch_bounds__(256) void k_bn2(
    const f16* __restrict__ t2f, float* __restrict__ out,
    const float* __restrict__ bn,
    const float* __restrict__ g2, const float* __restrict__ bb2, int N)
{
    __shared__ float sS[128], sB[128];
    const int tid = threadIdx.x;
    if (tid < 128) {
        float invN = 1.f / (float)N;
        float mu = bn[256 + tid] * invN;
        float var = bn[384 + tid] * invN - mu * mu;
        float scl = g2[tid] * rsqrtf(var + 1e-5f);
        sS[tid] = scl;
        sB[tid] = bb2[tid] - mu * scl;
    }
    __syncthreads();
    size_t idx = (size_t)blockIdx.x * 256 + tid;   // h4-group index
    size_t total = (size_t)N * 32;
    if (idx < total) {
        int gr = (int)(idx >> 5);
        int c0 = ((int)idx & 31) * 4;
        int slab = gr >> 7, m = (gr >> 4) & 7, rl = gr & 15;
        int w = c0 >> 5, nt = (c0 >> 4) & 1, q = (c0 >> 2) & 3;
        size_t fidx = (size_t)(((w * 8 + m) * 64 + (nt * 2 + (q >> 1)) * 16 + rl) * 8 +
                               (q & 1) * 4);
        h4 v = *(const h4*)(t2f + (size_t)slab * ND128 + fidx);
        float4 o;
        o.x = fmaf((float)v[0], sS[c0 + 0], sB[c0 + 0]);
        o.y = fmaf((float)v[1], sS[c0 + 1], sB[c0 + 1]);
        o.z = fmaf((float)v[2], sS[c0 + 2], sB[c0 + 2]);
        o.w = fmaf((float)v[3], sS[c0 + 3], sB[c0 + 3]);
        *(float4*)(out + (size_t)gr * 128 + c0) = o;
    }
}

extern "C" void kernel_launch(void* const* d_in, const int* in_sizes, int n_in,
                              void* d_out, int out_size, void* d_ws, size_t ws_size,
                              hipStream_t stream)
{
    const float* h   = (const float*)d_in[0];
    const int*   src = (const int*)d_in[1];
    const int*   dst = (const int*)d_in[2];
    const float* WQ  = (const float*)d_in[3];
    const float* WK  = (const float*)d_in[4];
    const float* WV  = (const float*)d_in[5];
    const float* WO  = (const float*)d_in[6];
    const float* bO  = (const float*)d_in[7];
    const float* W1  = (const float*)d_in[8];
    const float* b1  = (const float*)d_in[9];
    const float* W2  = (const float*)d_in[10];
    const float* b2  = (const float*)d_in[11];
    const float* g1  = (const float*)d_in[12];
    const float* bb1 = (const float*)d_in[13];
    const float* g2  = (const float*)d_in[14];
    const float* bb2 = (const float*)d_in[15];
    float* out = (float*)d_out;

    int N = in_sizes[0] / 128;
    int E = in_sizes[1];
    int slabs = (N + 127) / 128;
    int nsb = (N + 2047) / 2048;               // scan blocks (~25)
    int nhb = (E + 255) / 256;                 // edge blocks (~2500)
    const size_t B1 = (size_t)slabs * 32768;   // bytes of one f16 N_pad x 128 buffer

    char* Wp = (char*)d_ws;
    f16* hb  = (f16*)Wp;                       // h f16 frags, lives through oproj
    f16* Qb  = (f16*)(Wp + B1);                // B1
    unsigned char* KV8 = (unsigned char*)(Wp + 2 * B1);  // B1 (fp8 K|V 256B rows)
    f16* attnf = (f16*)(Wp + 3 * B1);          // B1; becomes t2f after ffn2
    f16* t1b = (f16*)(Wp + 4 * B1);            // B1
    f16* ub  = (f16*)(Wp + B1);                // 2*B1, overlays Qb+KV8 after attn
    f16* t2f = attnf;                          // attnf dead after oproj
    const size_t base = 5 * B1;
    f16* Wqb = (f16*)(Wp + base);
    f16* Wkb = (f16*)(Wp + base + 32768);
    f16* Wvb = (f16*)(Wp + base + 65536);
    f16* Wob = (f16*)(Wp + base + 98304);
    f16* W1b = (f16*)(Wp + base + 131072);
    f16* W2b = (f16*)(Wp + base + 196608);
    float* badj  = (float*)(Wp + base + 262144);
    float* sfold = (float*)(Wp + base + 263168);
    float* bfold = (float*)(Wp + base + 263680);
    float* bn    = (float*)(Wp + base + 264192);     // 512 floats (memset)
    int* bsum    = (int*)(Wp + base + 266240);       // 64 ints (memset)
    int* cursor  = (int*)(Wp + base + 266496);       // N ints (memset)
    int* rowptr  = (int*)(Wp + base + 266496 + (size_t)N * 4);
    int* csr     = (int*)(Wp + base + 266496 + (size_t)N * 8 + 8);

    // zero bn(2048) + bsum(256) + cursor(N*4) in one memset
    hipMemsetAsync(Wp + base + 264192, 0, 2304 + (size_t)N * 4, stream);
    k_prep_hist<<<nhb + slabs * 2, 256, 0, stream>>>(
        h, hb, WQ, WK, WV, WO, W2, Wqb, Wkb, Wvb, Wob, W2b, cursor, dst, N, E, nhb);
    k_qkv<<<dim3(slabs, 3), 256, 0, stream>>>(hb, Wqb, Wkb, Wvb, Qb, KV8, N);
    k_scanA<<<nsb, 256, 0, stream>>>(cursor, bsum, N);
    k_scanC<<<nsb, 256, 0, stream>>>(cursor, bsum, rowptr, cursor, N, nsb);
    k_scatter<<<nhb, 256, 0, stream>>>(src, dst, cursor, csr, E);
    k_attn<<<(N + 3) / 4, 256, 0, stream>>>(Qb, KV8, rowptr, csr, attnf, N);
    k_oproj<<<slabs, 256, 0, stream>>>(attnf, Wob, hb, bO, t1b, bn, N);
    k_fold1<<<256, 128, 0, stream>>>(bn, g1, bb1, W1, b1, W1b, badj, sfold, bfold, N);
    k_ffn1<<<dim3(slabs, 2), 256, 0, stream>>>(t1b, W1b, badj, ub, N);
    k_ffn2<<<slabs, 256, 0, stream>>>(ub, W2b, t1b, sfold, bfold, b2, t2f, bn, N);
    k_bn2<<<(int)(((size_t)N * 32 + 255) / 256), 256, 0, stream>>>(t2f, out, bn, g2, bb2, N);
}